// Round 10
// baseline (476.277 us; speedup 1.0000x reference)
//
#include <hip/hip_runtime.h>
#include <math.h>

// ---------------------------------------------------------------------------
// ObservationFusionModule — round 10: R9 (Tr=16 / 256 thr / 4 waves, passing)
// minus ALL prefetch register arrays. R9 post-mortem: prefetch state pushed
// VGPR 96->152 and occupancy DOWN to 11.8% — the cross-block-overlap idea was
// never tested. Lean registers buy resident blocks; TLP replaces ILP.
//   qk   = (Wk^T Wq) h + Wk^T bq
//   x2_s = relu(w1 @ relu(w0*log1p(st)+b0) + b1)      (kept in registers)
//   qk2  = w2^T qk
//   e_rs = qk2_r . x2_rs  (f32, ph4, wave-local + shfl broadcast)
//   score_s = (qk.obs_s + e_rs + h.NBK' + scc1)/16 + mask_s ; null analog
//   softmax; obar = sum p_s obs_s ; x2b = sum p_s x2_s
//   fused = Wv obar + (Wv w2) x2b + (1-w4)*(Wv b2 + bv) + w4*nv
//   gate  = sigmoid(Wg [h;fused] + bg) * any_real ; out = h + gate*LN(fused)
// ---------------------------------------------------------------------------

typedef __bf16 bf16x8 __attribute__((ext_vector_type(8)));
typedef float f32x4 __attribute__((ext_vector_type(4)));
typedef unsigned short u16;
typedef unsigned short u16x4 __attribute__((ext_vector_type(4)));

constexpr int Tr = 16;  // rows per block (4 waves x 4 rows)

// ws float offsets (W[0] = valid-dtype flag)
constexpr int OFF_BQK = 16;    // [256] Wk^T bq
constexpr int OFF_NBK = 272;   // [256] Wq^T (bk + Wk b2)
constexpr int OFF_NQ  = 528;   // [256] Wq^T null_key
constexpr int OFF_VB2P = 784;  // [256] Wv b2 + bv
constexpr int OFF_SCC = 1040;  // [0]=bq.(bk+Wk b2) [1]=bq.nk
// bf16 fragment region at W+2048 floats; [nt][kt][64][8] ushorts each
constexpr size_t UOFF_QK  = 0;       // 16x8
constexpr size_t UOFF_X2W = 65536;   // 8x4
constexpr size_t UOFF_QK2 = 81920;   // 8x8
constexpr size_t UOFF_V   = 114688;  // 16x8
constexpr size_t UOFF_V2  = 180224;  // 16x4
constexpr size_t UOFF_G   = 212992;  // 16x16

// shared layout (ushort units)
constexpr int SH_QK  = 0;     // [16][256] swz: qk ph1-ph4, fused ph5-ph7
constexpr int SH_QK2 = 4096;  // [16][128]: qk2 unswz ph2->ph4; x2b swz ph4->ph5
constexpr int SH_OB  = 6144;  // [16][256]: obar swz ph4->ph5; gate unswz ph6->ph7
constexpr int SMEM_BYTES = 20480 + (192 + 64) * 4;  // 21504

__device__ __forceinline__ float4 ld4(const float* p) { return *reinterpret_cast<const float4*>(p); }
__device__ __forceinline__ u16 f2bf(float x) { __bf16 b = (__bf16)x; return __builtin_bit_cast(u16, b); }
__device__ __forceinline__ float bf2f(u16 u) {
  unsigned v = ((unsigned)u) << 16;
  return __builtin_bit_cast(float, v);
}
__device__ __forceinline__ f32x4 mfma16(bf16x8 a, bf16x8 b, f32x4 c) {
  return __builtin_amdgcn_mfma_f32_16x16x32_bf16(a, b, c, 0, 0, 0);
}
__device__ __forceinline__ bf16x8 ldA8g(const u16* su, int base, int stride, int row, int kcol) {
  int off = (row * stride + kcol) ^ ((row & 7) << 3);
  return *reinterpret_cast<const bf16x8*>(su + base + off);
}
__device__ __forceinline__ bf16x8 ldB8(const u16* p, size_t off) {
  return *reinterpret_cast<const bf16x8*>(p + off);
}
__device__ __forceinline__ void stBF(u16* su, int base, int stride, int row, int col, float v) {
  int off = (row * stride + col) ^ ((row & 7) << 3);
  su[base + off] = f2bf(v);
}
__device__ __forceinline__ bf16x8 ldHfrag(const float* __restrict__ h, size_t row, int k) {
  const float4 a = ld4(h + row * 256 + k);
  const float4 b = ld4(h + row * 256 + k + 4);
  bf16x8 r;
  r[0] = (__bf16)a.x; r[1] = (__bf16)a.y; r[2] = (__bf16)a.z; r[3] = (__bf16)a.w;
  r[4] = (__bf16)b.x; r[5] = (__bf16)b.y; r[6] = (__bf16)b.z; r[7] = (__bf16)b.w;
  return r;
}
// LDS-only barrier: vmcnt NOT drained (register-destined global loads ride across)
__device__ __forceinline__ void barrier_lds() {
  asm volatile("s_waitcnt lgkmcnt(0)" ::: "memory");
  __builtin_amdgcn_s_barrier();
  asm volatile("" ::: "memory");
}

// --- valid_stack dtype probe ------------------------------------------------
__global__ void k_zero(int* __restrict__ f) {
  if (threadIdx.x == 0) f[0] = 0;
}
__global__ void k_flag(const unsigned int* __restrict__ v, int nwords, int* __restrict__ flag_out) {
  int my = 0;
  for (int i = blockIdx.x * blockDim.x + threadIdx.x; i < nwords; i += gridDim.x * blockDim.x) {
    const unsigned int w = v[i];
    if (w > 1u) my |= 1;
    if (((w & 0xFFu) > 1u) || (((w >> 8) & 0xFFu) > 1u) || (((w >> 16) & 0xFFu) > 1u) ||
        ((w >> 24) > 1u))
      my |= 2;
  }
  my |= __shfl_xor(my, 32, 64);
  my |= __shfl_xor(my, 16, 64);
  my |= __shfl_xor(my, 8, 64);
  my |= __shfl_xor(my, 4, 64);
  my |= __shfl_xor(my, 2, 64);
  my |= __shfl_xor(my, 1, 64);
  if ((threadIdx.x & 63) == 0 && my) atomicOr(flag_out, my);
}

// --- weight prep (unchanged, passing since R3) ------------------------------
__global__ void k_prep(const float* __restrict__ Wq, const float* __restrict__ bq,
                       const float* __restrict__ Wk, const float* __restrict__ bk,
                       const float* __restrict__ Wv, const float* __restrict__ bv,
                       const float* __restrict__ nk, const float* __restrict__ w1,
                       const float* __restrict__ w2, const float* __restrict__ b2,
                       const float* __restrict__ Wg, float* __restrict__ W) {
  const int b = blockIdx.x, t = threadIdx.x;
  u16* Wu = (u16*)(W + 2048);
  __shared__ float s_tile[48 * 260];
  if (b < 672) {
    int gemm, nt, kt, KT;
    size_t ubase;
    if (b < 128)      { gemm = 0; KT = 8;  kt = b & 7;          nt = b >> 3;          ubase = UOFF_QK; }
    else if (b < 160) { gemm = 1; KT = 4;  kt = (b - 128) & 3;  nt = (b - 128) >> 2;  ubase = UOFF_X2W; }
    else if (b < 224) { gemm = 2; KT = 8;  kt = (b - 160) & 7;  nt = (b - 160) >> 3;  ubase = UOFF_QK2; }
    else if (b < 352) { gemm = 3; KT = 8;  kt = (b - 224) & 7;  nt = (b - 224) >> 3;  ubase = UOFF_V; }
    else if (b < 416) { gemm = 4; KT = 4;  kt = (b - 352) & 3;  nt = (b - 352) >> 2;  ubase = UOFF_V2; }
    else              { gemm = 5; KT = 16; kt = (b - 416) & 15; nt = (b - 416) >> 4;  ubase = UOFF_G; }
    if (gemm == 0 || gemm == 4) {
      float* sA = s_tile;             // [16][260]
      float* sB = s_tile + 16 * 260;  // [32][260]
      const int n0 = nt * 16, k0 = kt * 32;
      if (gemm == 0) {
        for (int idx = t; idx < 4096; idx += 256) {
          const int o = idx >> 4, n = idx & 15;
          sA[n * 260 + o] = Wk[o * 256 + n0 + n];
        }
        for (int idx = t; idx < 8192; idx += 256) {
          const int o = idx >> 5, k = idx & 31;
          sB[k * 260 + o] = Wq[o * 256 + k0 + k];
        }
      } else {
        for (int idx = t; idx < 4096; idx += 256) {
          const int n = idx >> 8, o = idx & 255;
          sA[n * 260 + o] = Wv[(size_t)(n0 + n) * 256 + o];
        }
        for (int idx = t; idx < 8192; idx += 256) {
          const int o = idx >> 5, k = idx & 31;
          sB[k * 260 + o] = w2[o * 128 + k0 + k];
        }
      }
      __syncthreads();
      for (int e = t; e < 512; e += 256) {
        const int l = e >> 3, j = e & 7;
        const int n = l & 15;
        const int k = ((l >> 4) << 3) + j;
        const float4* pa = (const float4*)(sA + n * 260);
        const float4* pb = (const float4*)(sB + k * 260);
        float acc = 0.f;
#pragma unroll 8
        for (int o4 = 0; o4 < 64; ++o4) {
          const float4 a = pa[o4], bb = pb[o4];
          acc += a.x * bb.x + a.y * bb.y + a.z * bb.z + a.w * bb.w;
        }
        Wu[ubase + (size_t)(nt * KT + kt) * 512 + e] = f2bf(acc);
      }
    } else {
      for (int e = t; e < 512; e += 256) {
        const int l = e >> 3, j = e & 7;
        const int n = nt * 16 + (l & 15);
        const int k = kt * 32 + ((l >> 4) << 3) + j;
        float val;
        if (gemm == 1)      val = w1[n * 128 + k];
        else if (gemm == 2) val = w2[k * 128 + n];
        else if (gemm == 3) val = Wv[n * 256 + k];
        else                val = Wg[n * 512 + k];
        Wu[ubase + (size_t)(nt * KT + kt) * 512 + e] = f2bf(val);
      }
    }
  } else {  // vectors + scalars
    float* s_u = s_tile;
    float a = 0.f;
    for (int hh = 0; hh < 256; ++hh) a = fmaf(Wk[t * 256 + hh], b2[hh], a);
    s_u[t] = a + bk[t];
    __syncthreads();
    float a1 = 0.f, a2 = 0.f, a3 = 0.f, a4 = 0.f;
    for (int o = 0; o < 256; ++o) {
      a1 = fmaf(Wq[o * 256 + t], s_u[o], a1);
      a2 = fmaf(Wq[o * 256 + t], nk[o], a2);
      a3 = fmaf(Wk[o * 256 + t], bq[o], a3);
      a4 = fmaf(Wv[t * 256 + o], b2[o], a4);
    }
    W[OFF_NBK + t] = a1;
    W[OFF_NQ + t] = a2;
    W[OFF_BQK + t] = a3;
    W[OFF_VB2P + t] = a4 + bv[t];
    if (t == 0) {
      float c1 = 0.f, c2 = 0.f;
      for (int o = 0; o < 256; ++o) {
        c1 = fmaf(bq[o], s_u[o], c1);
        c2 = fmaf(bq[o], nk[o], c2);
      }
      W[OFF_SCC] = c1;
      W[OFF_SCC + 1] = c2;
    }
  }
}

// --- main fused kernel (R9 structure, lean registers) -----------------------
// s_sc row stride 12: 0-3 mask, 4 sbk, 5 snull, 6 anyreal, 7 w4, 8 mu, 9 rstd
__launch_bounds__(256) __global__
void k_main(const float* __restrict__ h, const float* __restrict__ obs,
            const float* __restrict__ stal, const void* __restrict__ valid,
            const float* __restrict__ w0, const float* __restrict__ b0,
            const float* __restrict__ b1, const float* __restrict__ bg,
            const float* __restrict__ lnw, const float* __restrict__ lnb,
            const float* __restrict__ nv, const float* __restrict__ W,
            const int* __restrict__ flagp, float* __restrict__ out) {
  extern __shared__ char smraw[];
  u16* su = (u16*)smraw;
  float* s_sc = (float*)(smraw + 20480);  // [16][12]
  float* s_x0 = s_sc + 192;               // [64]
  const u16* Wu = (const u16*)(W + 2048);
  const int t = threadIdx.x;
  const int lane = t & 63, wv = t >> 6;   // wv 0..3
  const int l16 = lane & 15, g = lane >> 4;
  const size_t row0 = (size_t)blockIdx.x * Tr;
  const int vv = *flagp;
  const int mode = ((vv & 1) == 0) ? 0 : (((vv & 2) == 0) ? 1 : 2);  // 0=i32 1=u8 2=f32

  // ---- ph0: masks / x0 / any_real -----------------------------------------
  if (t < 64) {
    const int r = t >> 2, s = t & 3;
    const size_t idx = (row0 + r) * 4 + s;
    bool vb;
    if (mode == 0) vb = ((const int*)valid)[idx] != 0;
    else if (mode == 1) vb = ((const unsigned char*)valid)[idx] != 0;
    else vb = ((const float*)valid)[idx] != 0.f;
    s_sc[r * 12 + s] = vb ? 0.f : -5.f;
    s_x0[t] = log1pf(stal[idx]);
  } else if (t < 80) {
    const int r = t - 64;
    const size_t base = (row0 + r) * 4;
    bool any = false;
    for (int s = 0; s < 4; ++s) {
      bool vb;
      if (mode == 0) vb = ((const int*)valid)[base + s] != 0;
      else if (mode == 1) vb = ((const unsigned char*)valid)[base + s] != 0;
      else vb = ((const float*)valid)[base + s] != 0.f;
      any |= vb;
    }
    s_sc[r * 12 + 6] = any ? 1.f : 0.f;
  }
  barrier_lds();  // B0

  // ---- ph1: per-row score consts + QK gemm ---------------------------------
  {
    const int task = lane >> 3, sub = lane & 7;
    const int r = wv * 4 + (task >> 1);
    const int which = task & 1;
    const float* vecp = which ? (W + OFF_NQ) : (W + OFF_NBK);
    const float* hp = h + (row0 + r) * 256 + sub * 32;
    const float* vp = vecp + sub * 32;
    float acc = 0.f;
#pragma unroll
    for (int j = 0; j < 8; ++j) {
      const float4 hv = ld4(hp + j * 4);
      const float4 vvv = ld4(vp + j * 4);
      acc += hv.x * vvv.x + hv.y * vvv.y + hv.z * vvv.z + hv.w * vvv.w;
    }
    acc += __shfl_xor(acc, 1, 64);
    acc += __shfl_xor(acc, 2, 64);
    acc += __shfl_xor(acc, 4, 64);
    if (sub == 0) s_sc[r * 12 + 4 + which] = acc + W[OFF_SCC + which];
  }
  {
    f32x4 acc[4] = {{0.f, 0.f, 0.f, 0.f}, {0.f, 0.f, 0.f, 0.f},
                    {0.f, 0.f, 0.f, 0.f}, {0.f, 0.f, 0.f, 0.f}};
#pragma unroll
    for (int kt = 0; kt < 8; ++kt) {
      const bf16x8 a0 = ldHfrag(h, row0 + l16, kt * 32 + g * 8);
#pragma unroll
      for (int n4 = 0; n4 < 4; ++n4) {
        const int nt = wv * 4 + n4;
        const bf16x8 b = ldB8(Wu, UOFF_QK + (size_t)((nt * 8 + kt) * 64 + lane) * 8);
        acc[n4] = mfma16(a0, b, acc[n4]);
      }
    }
#pragma unroll
    for (int n4 = 0; n4 < 4; ++n4) {
      const int col = (wv * 4 + n4) * 16 + l16;
      const float bqk = W[OFF_BQK + col];
#pragma unroll
      for (int reg = 0; reg < 4; ++reg)
        stBF(su, SH_QK, 256, g * 4 + reg, col, acc[n4][reg] + bqk);
    }
  }
  barrier_lds();  // B1

  // ---- ph2: QK2 gemm + X2 gemm (x2 in regs) --------------------------------
  u16x4 x2p[8];  // x2[r=wv*4+g][s][col=nt*16+l16], retained to ph4
  {
    f32x4 acc2[2] = {{0.f, 0.f, 0.f, 0.f}, {0.f, 0.f, 0.f, 0.f}};
#pragma unroll
    for (int kt = 0; kt < 8; ++kt) {
      const bf16x8 a = ldA8g(su, SH_QK, 256, l16, kt * 32 + g * 8);
#pragma unroll
      for (int n2 = 0; n2 < 2; ++n2) {
        const bf16x8 b = ldB8(Wu, UOFF_QK2 + (size_t)(((wv * 2 + n2) * 8 + kt) * 64 + lane) * 8);
        acc2[n2] = mfma16(a, b, acc2[n2]);
      }
    }
    f32x4 accx[8] = {{0.f,0.f,0.f,0.f},{0.f,0.f,0.f,0.f},{0.f,0.f,0.f,0.f},{0.f,0.f,0.f,0.f},
                     {0.f,0.f,0.f,0.f},{0.f,0.f,0.f,0.f},{0.f,0.f,0.f,0.f},{0.f,0.f,0.f,0.f}};
    const float x0v = s_x0[wv * 16 + l16];
#pragma unroll
    for (int kt = 0; kt < 4; ++kt) {
      const int k0 = kt * 32 + g * 8;
      const float4 wa = ld4(w0 + k0), wb = ld4(w0 + k0 + 4);
      const float4 ba = ld4(b0 + k0), bb = ld4(b0 + k0 + 4);
      bf16x8 a;
      a[0] = (__bf16)fmaxf(fmaf(wa.x, x0v, ba.x), 0.f);
      a[1] = (__bf16)fmaxf(fmaf(wa.y, x0v, ba.y), 0.f);
      a[2] = (__bf16)fmaxf(fmaf(wa.z, x0v, ba.z), 0.f);
      a[3] = (__bf16)fmaxf(fmaf(wa.w, x0v, ba.w), 0.f);
      a[4] = (__bf16)fmaxf(fmaf(wb.x, x0v, bb.x), 0.f);
      a[5] = (__bf16)fmaxf(fmaf(wb.y, x0v, bb.y), 0.f);
      a[6] = (__bf16)fmaxf(fmaf(wb.z, x0v, bb.z), 0.f);
      a[7] = (__bf16)fmaxf(fmaf(wb.w, x0v, bb.w), 0.f);
#pragma unroll
      for (int nt = 0; nt < 8; ++nt) {
        const bf16x8 b = ldB8(Wu, UOFF_X2W + (size_t)((nt * 4 + kt) * 64 + lane) * 8);
        accx[nt] = mfma16(a, b, accx[nt]);
      }
    }
    // epilogues: qk2 -> LDS unswz; x2 -> regs
#pragma unroll
    for (int n2 = 0; n2 < 2; ++n2) {
      const int col = (wv * 2 + n2) * 16 + l16;
#pragma unroll
      for (int reg = 0; reg < 4; ++reg)
        su[SH_QK2 + (g * 4 + reg) * 128 + col] = f2bf(acc2[n2][reg]);
    }
#pragma unroll
    for (int nt = 0; nt < 8; ++nt) {
      const int col = nt * 16 + l16;
      const float b1c = b1[col];
      u16x4 xp;
#pragma unroll
      for (int reg = 0; reg < 4; ++reg) xp[reg] = f2bf(fmaxf(accx[nt][reg] + b1c, 0.f));
      x2p[nt] = xp;
    }
  }
  barrier_lds();  // B2

  // ---- ph4: e; obs stream; scores/softmax; obar,x2b ------------------------
  {
    float ep0 = 0.f, ep1 = 0.f, ep2 = 0.f, ep3 = 0.f;
    const int r_own = wv * 4 + g;
#pragma unroll
    for (int nt = 0; nt < 8; ++nt) {
      const float q2v = bf2f(su[SH_QK2 + r_own * 128 + nt * 16 + l16]);
      ep0 = fmaf(bf2f(x2p[nt][0]), q2v, ep0);
      ep1 = fmaf(bf2f(x2p[nt][1]), q2v, ep1);
      ep2 = fmaf(bf2f(x2p[nt][2]), q2v, ep2);
      ep3 = fmaf(bf2f(x2p[nt][3]), q2v, ep3);
    }
#pragma unroll
    for (int sh = 1; sh <= 8; sh <<= 1) {
      ep0 += __shfl_xor(ep0, sh, 64);
      ep1 += __shfl_xor(ep1, sh, 64);
      ep2 += __shfl_xor(ep2, sh, 64);
      ep3 += __shfl_xor(ep3, sh, 64);
    }
    float px0 = 0.f, px1 = 0.f, px2 = 0.f, px3 = 0.f;
#pragma unroll
    for (int rr = 0; rr < 4; ++rr) {
      const int r = wv * 4 + rr;
      float4 ov[4];
#pragma unroll
      for (int s = 0; s < 4; ++s)
        ov[s] = ld4(obs + ((row0 + r) * 4 + s) * 256 + lane * 4);
      const int qoff = (r * 256 + lane * 4) ^ ((r & 7) << 3);
      const u16x4 qv4 = *reinterpret_cast<const u16x4*>(su + SH_QK + qoff);
      const float q0 = bf2f(qv4[0]), q1 = bf2f(qv4[1]), q2 = bf2f(qv4[2]), q3 = bf2f(qv4[3]);
      const float sbk = s_sc[r * 12 + 4];
      const float e0 = __shfl(ep0, rr << 4, 64);
      const float e1 = __shfl(ep1, rr << 4, 64);
      const float e2 = __shfl(ep2, rr << 4, 64);
      const float e3 = __shfl(ep3, rr << 4, 64);
      float sc[4];
#pragma unroll
      for (int s = 0; s < 4; ++s)
        sc[s] = q0 * ov[s].x + q1 * ov[s].y + q2 * ov[s].z + q3 * ov[s].w;
#pragma unroll
      for (int sh = 1; sh <= 32; sh <<= 1) {
#pragma unroll
        for (int s = 0; s < 4; ++s) sc[s] += __shfl_xor(sc[s], sh, 64);
      }
      sc[0] = (sc[0] + e0 + sbk) * 0.0625f + s_sc[r * 12 + 0];
      sc[1] = (sc[1] + e1 + sbk) * 0.0625f + s_sc[r * 12 + 1];
      sc[2] = (sc[2] + e2 + sbk) * 0.0625f + s_sc[r * 12 + 2];
      sc[3] = (sc[3] + e3 + sbk) * 0.0625f + s_sc[r * 12 + 3];
      const float snv = s_sc[r * 12 + 5] * 0.0625f;
      const float m = fmaxf(fmaxf(fmaxf(sc[0], sc[1]), fmaxf(sc[2], sc[3])), snv);
      const float p0e = __expf(sc[0] - m), p1e = __expf(sc[1] - m);
      const float p2e = __expf(sc[2] - m), p3e = __expf(sc[3] - m);
      const float pne = __expf(snv - m);
      const float invD = 1.f / (p0e + p1e + p2e + p3e + pne);
      const float p0 = p0e * invD, p1 = p1e * invD, p2 = p2e * invD, p3 = p3e * invD;
      const int ooff = (r * 256 + lane * 4) ^ ((r & 7) << 3);
      u16x4 o4;
      o4[0] = f2bf(p0 * ov[0].x + p1 * ov[1].x + p2 * ov[2].x + p3 * ov[3].x);
      o4[1] = f2bf(p0 * ov[0].y + p1 * ov[1].y + p2 * ov[2].y + p3 * ov[3].y);
      o4[2] = f2bf(p0 * ov[0].z + p1 * ov[1].z + p2 * ov[2].z + p3 * ov[3].z);
      o4[3] = f2bf(p0 * ov[0].w + p1 * ov[1].w + p2 * ov[2].w + p3 * ov[3].w);
      *reinterpret_cast<u16x4*>(su + SH_OB + ooff) = o4;
      if (lane == 0) s_sc[r * 12 + 7] = pne * invD;  // w4
      px0 = (rr == g) ? p0 : px0;
      px1 = (rr == g) ? p1 : px1;
      px2 = (rr == g) ? p2 : px2;
      px3 = (rr == g) ? p3 : px3;
    }
    // x2b into own (wave-private) SH_QK2 row, swizzled for ph5 A-reads
#pragma unroll
    for (int nt = 0; nt < 8; ++nt) {
      const int col = nt * 16 + l16;
      const float v = px0 * bf2f(x2p[nt][0]) + px1 * bf2f(x2p[nt][1]) +
                      px2 * bf2f(x2p[nt][2]) + px3 * bf2f(x2p[nt][3]);
      su[SH_QK2 + ((r_own * 128 + col) ^ ((r_own & 7) << 3))] = f2bf(v);
    }
  }
  barrier_lds();  // B3

  // ---- ph5: fused = V(obar) + V2(x2b) + (1-w4)*vb2p + w4*nv ----------------
  {
    f32x4 acc[4] = {{0.f, 0.f, 0.f, 0.f}, {0.f, 0.f, 0.f, 0.f},
                    {0.f, 0.f, 0.f, 0.f}, {0.f, 0.f, 0.f, 0.f}};
#pragma unroll
    for (int kt = 0; kt < 8; ++kt) {
      const bf16x8 a0 = ldA8g(su, SH_OB, 256, l16, kt * 32 + g * 8);
#pragma unroll
      for (int n4 = 0; n4 < 4; ++n4) {
        const int nt = wv * 4 + n4;
        const bf16x8 b = ldB8(Wu, UOFF_V + (size_t)((nt * 8 + kt) * 64 + lane) * 8);
        acc[n4] = mfma16(a0, b, acc[n4]);
      }
    }
#pragma unroll
    for (int kt = 0; kt < 4; ++kt) {
      const bf16x8 a0 = ldA8g(su, SH_QK2, 128, l16, kt * 32 + g * 8);
#pragma unroll
      for (int n4 = 0; n4 < 4; ++n4) {
        const int nt = wv * 4 + n4;
        const bf16x8 b = ldB8(Wu, UOFF_V2 + (size_t)((nt * 4 + kt) * 64 + lane) * 8);
        acc[n4] = mfma16(a0, b, acc[n4]);
      }
    }
#pragma unroll
    for (int n4 = 0; n4 < 4; ++n4) {
      const int col = (wv * 4 + n4) * 16 + l16;
      const float vb = W[OFF_VB2P + col];
      const float nvc = nv[col];
#pragma unroll
      for (int reg = 0; reg < 4; ++reg) {
        const int row = g * 4 + reg;
        const float w4v = s_sc[row * 12 + 7];
        const float f = acc[n4][reg] + (1.f - w4v) * vb + w4v * nvc;
        stBF(su, SH_QK, 256, row, col, f);
      }
    }
  }
  barrier_lds();  // B4

  // ---- ph6: LN stats + gate gemm ------------------------------------------
  {
#pragma unroll
    for (int rr = 0; rr < 4; ++rr) {
      const int r = wv * 4 + rr;
      const int foff = (r * 256 + lane * 4) ^ ((r & 7) << 3);
      const u16x4 f4 = *reinterpret_cast<const u16x4*>(su + SH_QK + foff);
      const float f0 = bf2f(f4[0]), f1 = bf2f(f4[1]), f2v = bf2f(f4[2]), f3 = bf2f(f4[3]);
      float sum = f0 + f1 + f2v + f3;
      float sq = f0 * f0 + f1 * f1 + f2v * f2v + f3 * f3;
#pragma unroll
      for (int sh = 1; sh <= 32; sh <<= 1) {
        sum += __shfl_xor(sum, sh, 64);
        sq += __shfl_xor(sq, sh, 64);
      }
      if (lane == 0) {
        const float mu = sum * (1.f / 256.f);
        const float var = sq * (1.f / 256.f) - mu * mu;
        s_sc[r * 12 + 8] = mu;
        s_sc[r * 12 + 9] = rsqrtf(var + 1e-5f);
      }
    }
  }
  {
    f32x4 acc[4] = {{0.f, 0.f, 0.f, 0.f}, {0.f, 0.f, 0.f, 0.f},
                    {0.f, 0.f, 0.f, 0.f}, {0.f, 0.f, 0.f, 0.f}};
#pragma unroll
    for (int kt = 0; kt < 8; ++kt) {
      const bf16x8 a0 = ldHfrag(h, row0 + l16, kt * 32 + g * 8);
#pragma unroll
      for (int n4 = 0; n4 < 4; ++n4) {
        const int nt = wv * 4 + n4;
        const bf16x8 b = ldB8(Wu, UOFF_G + (size_t)((nt * 16 + kt) * 64 + lane) * 8);
        acc[n4] = mfma16(a0, b, acc[n4]);
      }
    }
#pragma unroll
    for (int kt = 8; kt < 16; ++kt) {
      const bf16x8 a0 = ldA8g(su, SH_QK, 256, l16, (kt - 8) * 32 + g * 8);
#pragma unroll
      for (int n4 = 0; n4 < 4; ++n4) {
        const int nt = wv * 4 + n4;
        const bf16x8 b = ldB8(Wu, UOFF_G + (size_t)((nt * 16 + kt) * 64 + lane) * 8);
        acc[n4] = mfma16(a0, b, acc[n4]);
      }
    }
#pragma unroll
    for (int n4 = 0; n4 < 4; ++n4) {
      const int col = (wv * 4 + n4) * 16 + l16;
      const float bgc = bg[col];
#pragma unroll
      for (int reg = 0; reg < 4; ++reg) {
        const int row = g * 4 + reg;
        const float z = acc[n4][reg] + bgc;
        su[SH_OB + row * 256 + col] = f2bf(1.f / (1.f + __expf(-z)));
      }
    }
  }
  barrier_lds();  // B5

  // ---- ph7: out = h + gate*any_real*((fused-mu)*rstd*lnw+lnb) -------------
#pragma unroll
  for (int i = 0; i < Tr; ++i) {
    const float mu = s_sc[i * 12 + 8], inv = s_sc[i * 12 + 9], ar = s_sc[i * 12 + 6];
    const float f = bf2f(su[SH_QK + ((i * 256 + t) ^ ((i & 7) << 3))]);
    const float gt = bf2f(su[SH_OB + i * 256 + t]) * ar;
    const float upd = (f - mu) * inv * lnw[t] + lnb[t];
    out[(row0 + i) * 256 + t] = h[(row0 + i) * 256 + t] + gt * upd;
  }
}

extern "C" void kernel_launch(void* const* d_in, const int* in_sizes, int n_in, void* d_out,
                              int out_size, void* d_ws, size_t ws_size, hipStream_t stream) {
  const float* h = (const float*)d_in[0];
  const float* obs = (const float*)d_in[1];
  const float* st = (const float*)d_in[2];
  const void* vd = d_in[3];
  const float* Wq = (const float*)d_in[4];
  const float* bq = (const float*)d_in[5];
  const float* Wk = (const float*)d_in[6];
  const float* bk = (const float*)d_in[7];
  const float* Wv = (const float*)d_in[8];
  const float* bv = (const float*)d_in[9];
  const float* nk = (const float*)d_in[10];
  const float* nv = (const float*)d_in[11];
  const float* w0 = (const float*)d_in[12];
  const float* b0 = (const float*)d_in[13];
  const float* w1 = (const float*)d_in[14];
  const float* b1 = (const float*)d_in[15];
  const float* w2 = (const float*)d_in[16];
  const float* b2 = (const float*)d_in[17];
  const float* Wg = (const float*)d_in[18];
  const float* bg = (const float*)d_in[19];
  const float* lnw = (const float*)d_in[20];
  const float* lnb = (const float*)d_in[21];
  float* out = (float*)d_out;
  float* W = (float*)d_ws;
  const int L = in_sizes[0] / 256;

  k_zero<<<1, 64, 0, stream>>>((int*)d_ws);
  k_flag<<<256, 256, 0, stream>>>((const unsigned int*)vd, L, (int*)d_ws);
  k_prep<<<673, 256, 0, stream>>>(Wq, bq, Wk, bk, Wv, bv, nk, w1, w2, b2, Wg, W);
  k_main<<<L / Tr, 256, SMEM_BYTES, stream>>>(h, obs, st, vd, w0, b0, b1, bg, lnw, lnb, nv, W,
                                              (const int*)d_ws, out);
}

// Round 11
// 374.877 us; speedup vs baseline: 1.2705x; 1.2705x over previous
//
#include <hip/hip_runtime.h>
#include <math.h>

// ---------------------------------------------------------------------------
// ObservationFusionModule — round 11: R6 monolith (best, 363us k_main) with
// STATIC __shared__ instead of dynamic. 10-round invariant: occupancy pinned
// at exactly 1 block/CU in every config (4w->11.8%, 8w->23.5%) despite
// VGPR/LDS budgets allowing 2-3 blocks; LDS_Block_Size reports 0 for every
// dynamic-smem launch. Hypothesis: dynamic-LDS path reserves worst-case LDS,
// capping residency at 1 block. Static allocation (43008B) tests it; math
// is bit-identical to the passing R6.
// ---------------------------------------------------------------------------

typedef __bf16 bf16x8 __attribute__((ext_vector_type(8)));
typedef float f32x4 __attribute__((ext_vector_type(4)));
typedef unsigned short u16;
typedef unsigned short u16x4 __attribute__((ext_vector_type(4)));

constexpr int Tr = 32;  // rows per block (8 waves x 4 rows)

// ws float offsets (W[0] = valid-dtype flag)
constexpr int OFF_BQK = 16;    // [256] Wk^T bq
constexpr int OFF_NBK = 272;   // [256] Wq^T (bk + Wk b2)
constexpr int OFF_NQ  = 528;   // [256] Wq^T null_key
constexpr int OFF_VB2P = 784;  // [256] Wv b2 + bv
constexpr int OFF_SCC = 1040;  // [0]=bq.(bk+Wk b2) [1]=bq.nk
// bf16 fragment region at W+2048 floats; [nt][kt][64][8] ushorts each
constexpr size_t UOFF_QK  = 0;       // 16x8
constexpr size_t UOFF_X2W = 65536;   // 8x4
constexpr size_t UOFF_QK2 = 81920;   // 8x8
constexpr size_t UOFF_V   = 114688;  // 16x8
constexpr size_t UOFF_V2  = 180224;  // 16x4
constexpr size_t UOFF_G   = 212992;  // 16x16

// shared layout (ushort units)
constexpr int SH_QK  = 0;      // [32][256] swz: qk ph1-ph4, fused ph5-ph7
constexpr int SH_QK2 = 8192;   // [32][128]: qk2 unswz ph2->ph4; x2b swz ph4->ph5
constexpr int SH_OB  = 12288;  // [32][256]: obar swz ph4->ph5; gate unswz ph6->ph7

__device__ __forceinline__ float4 ld4(const float* p) { return *reinterpret_cast<const float4*>(p); }
__device__ __forceinline__ u16 f2bf(float x) { __bf16 b = (__bf16)x; return __builtin_bit_cast(u16, b); }
__device__ __forceinline__ float bf2f(u16 u) {
  unsigned v = ((unsigned)u) << 16;
  return __builtin_bit_cast(float, v);
}
__device__ __forceinline__ f32x4 mfma16(bf16x8 a, bf16x8 b, f32x4 c) {
  return __builtin_amdgcn_mfma_f32_16x16x32_bf16(a, b, c, 0, 0, 0);
}
__device__ __forceinline__ bf16x8 ldA8g(const u16* su, int base, int stride, int row, int kcol) {
  int off = (row * stride + kcol) ^ ((row & 7) << 3);
  return *reinterpret_cast<const bf16x8*>(su + base + off);
}
__device__ __forceinline__ bf16x8 ldB8(const u16* p, size_t off) {
  return *reinterpret_cast<const bf16x8*>(p + off);
}
__device__ __forceinline__ void stBF(u16* su, int base, int stride, int row, int col, float v) {
  int off = (row * stride + col) ^ ((row & 7) << 3);
  su[base + off] = f2bf(v);
}
__device__ __forceinline__ bf16x8 ldHfrag(const float* __restrict__ h, size_t row, int k) {
  const float4 a = ld4(h + row * 256 + k);
  const float4 b = ld4(h + row * 256 + k + 4);
  bf16x8 r;
  r[0] = (__bf16)a.x; r[1] = (__bf16)a.y; r[2] = (__bf16)a.z; r[3] = (__bf16)a.w;
  r[4] = (__bf16)b.x; r[5] = (__bf16)b.y; r[6] = (__bf16)b.z; r[7] = (__bf16)b.w;
  return r;
}
// LDS-only barrier: vmcnt NOT drained (register-destined global loads ride across)
__device__ __forceinline__ void barrier_lds() {
  asm volatile("s_waitcnt lgkmcnt(0)" ::: "memory");
  __builtin_amdgcn_s_barrier();
  asm volatile("" ::: "memory");
}

// --- valid_stack dtype probe ------------------------------------------------
__global__ void k_zero(int* __restrict__ f) {
  if (threadIdx.x == 0) f[0] = 0;
}
__global__ void k_flag(const unsigned int* __restrict__ v, int nwords, int* __restrict__ flag_out) {
  int my = 0;
  for (int i = blockIdx.x * blockDim.x + threadIdx.x; i < nwords; i += gridDim.x * blockDim.x) {
    const unsigned int w = v[i];
    if (w > 1u) my |= 1;
    if (((w & 0xFFu) > 1u) || (((w >> 8) & 0xFFu) > 1u) || (((w >> 16) & 0xFFu) > 1u) ||
        ((w >> 24) > 1u))
      my |= 2;
  }
  my |= __shfl_xor(my, 32, 64);
  my |= __shfl_xor(my, 16, 64);
  my |= __shfl_xor(my, 8, 64);
  my |= __shfl_xor(my, 4, 64);
  my |= __shfl_xor(my, 2, 64);
  my |= __shfl_xor(my, 1, 64);
  if ((threadIdx.x & 63) == 0 && my) atomicOr(flag_out, my);
}

// --- weight prep (unchanged, passing since R3) ------------------------------
__global__ void k_prep(const float* __restrict__ Wq, const float* __restrict__ bq,
                       const float* __restrict__ Wk, const float* __restrict__ bk,
                       const float* __restrict__ Wv, const float* __restrict__ bv,
                       const float* __restrict__ nk, const float* __restrict__ w1,
                       const float* __restrict__ w2, const float* __restrict__ b2,
                       const float* __restrict__ Wg, float* __restrict__ W) {
  const int b = blockIdx.x, t = threadIdx.x;
  u16* Wu = (u16*)(W + 2048);
  __shared__ float s_tile[48 * 260];
  if (b < 672) {
    int gemm, nt, kt, KT;
    size_t ubase;
    if (b < 128)      { gemm = 0; KT = 8;  kt = b & 7;          nt = b >> 3;          ubase = UOFF_QK; }
    else if (b < 160) { gemm = 1; KT = 4;  kt = (b - 128) & 3;  nt = (b - 128) >> 2;  ubase = UOFF_X2W; }
    else if (b < 224) { gemm = 2; KT = 8;  kt = (b - 160) & 7;  nt = (b - 160) >> 3;  ubase = UOFF_QK2; }
    else if (b < 352) { gemm = 3; KT = 8;  kt = (b - 224) & 7;  nt = (b - 224) >> 3;  ubase = UOFF_V; }
    else if (b < 416) { gemm = 4; KT = 4;  kt = (b - 352) & 3;  nt = (b - 352) >> 2;  ubase = UOFF_V2; }
    else              { gemm = 5; KT = 16; kt = (b - 416) & 15; nt = (b - 416) >> 4;  ubase = UOFF_G; }
    if (gemm == 0 || gemm == 4) {
      float* sA = s_tile;             // [16][260]
      float* sB = s_tile + 16 * 260;  // [32][260]
      const int n0 = nt * 16, k0 = kt * 32;
      if (gemm == 0) {
        for (int idx = t; idx < 4096; idx += 256) {
          const int o = idx >> 4, n = idx & 15;
          sA[n * 260 + o] = Wk[o * 256 + n0 + n];
        }
        for (int idx = t; idx < 8192; idx += 256) {
          const int o = idx >> 5, k = idx & 31;
          sB[k * 260 + o] = Wq[o * 256 + k0 + k];
        }
      } else {
        for (int idx = t; idx < 4096; idx += 256) {
          const int n = idx >> 8, o = idx & 255;
          sA[n * 260 + o] = Wv[(size_t)(n0 + n) * 256 + o];
        }
        for (int idx = t; idx < 8192; idx += 256) {
          const int o = idx >> 5, k = idx & 31;
          sB[k * 260 + o] = w2[o * 128 + k0 + k];
        }
      }
      __syncthreads();
      for (int e = t; e < 512; e += 256) {
        const int l = e >> 3, j = e & 7;
        const int n = l & 15;
        const int k = ((l >> 4) << 3) + j;
        const float4* pa = (const float4*)(sA + n * 260);
        const float4* pb = (const float4*)(sB + k * 260);
        float acc = 0.f;
#pragma unroll 8
        for (int o4 = 0; o4 < 64; ++o4) {
          const float4 a = pa[o4], bb = pb[o4];
          acc += a.x * bb.x + a.y * bb.y + a.z * bb.z + a.w * bb.w;
        }
        Wu[ubase + (size_t)(nt * KT + kt) * 512 + e] = f2bf(acc);
      }
    } else {
      for (int e = t; e < 512; e += 256) {
        const int l = e >> 3, j = e & 7;
        const int n = nt * 16 + (l & 15);
        const int k = kt * 32 + ((l >> 4) << 3) + j;
        float val;
        if (gemm == 1)      val = w1[n * 128 + k];
        else if (gemm == 2) val = w2[k * 128 + n];
        else if (gemm == 3) val = Wv[n * 256 + k];
        else                val = Wg[n * 512 + k];
        Wu[ubase + (size_t)(nt * KT + kt) * 512 + e] = f2bf(val);
      }
    }
  } else {  // vectors + scalars
    float* s_u = s_tile;
    float a = 0.f;
    for (int hh = 0; hh < 256; ++hh) a = fmaf(Wk[t * 256 + hh], b2[hh], a);
    s_u[t] = a + bk[t];
    __syncthreads();
    float a1 = 0.f, a2 = 0.f, a3 = 0.f, a4 = 0.f;
    for (int o = 0; o < 256; ++o) {
      a1 = fmaf(Wq[o * 256 + t], s_u[o], a1);
      a2 = fmaf(Wq[o * 256 + t], nk[o], a2);
      a3 = fmaf(Wk[o * 256 + t], bq[o], a3);
      a4 = fmaf(Wv[t * 256 + o], b2[o], a4);
    }
    W[OFF_NBK + t] = a1;
    W[OFF_NQ + t] = a2;
    W[OFF_BQK + t] = a3;
    W[OFF_VB2P + t] = a4 + bv[t];
    if (t == 0) {
      float c1 = 0.f, c2 = 0.f;
      for (int o = 0; o < 256; ++o) {
        c1 = fmaf(bq[o], s_u[o], c1);
        c2 = fmaf(bq[o], nk[o], c2);
      }
      W[OFF_SCC] = c1;
      W[OFF_SCC + 1] = c2;
    }
  }
}

// --- main fused kernel (R6 verbatim, STATIC shared) -------------------------
// s_sc row stride 12: 0-3 mask, 4 sbk, 5 snull, 6 anyreal, 7 w4, 8 mu, 9 rstd
__launch_bounds__(512) __global__
void k_main(const float* __restrict__ h, const float* __restrict__ obs,
            const float* __restrict__ stal, const void* __restrict__ valid,
            const float* __restrict__ w0, const float* __restrict__ b0,
            const float* __restrict__ b1, const float* __restrict__ bg,
            const float* __restrict__ lnw, const float* __restrict__ lnb,
            const float* __restrict__ nv, const float* __restrict__ W,
            const int* __restrict__ flagp, float* __restrict__ out) {
  __shared__ u16 su[20480];     // 40960 B: SH_QK + SH_QK2 + SH_OB
  __shared__ float s_sc[384];   // [32][12]
  __shared__ float s_x0[128];
  const u16* Wu = (const u16*)(W + 2048);
  const int t = threadIdx.x;
  const int lane = t & 63, wv = t >> 6;   // wv 0..7
  const int l16 = lane & 15, g = lane >> 4;
  const size_t row0 = (size_t)blockIdx.x * Tr;
  const int vv = *flagp;
  const int mode = ((vv & 1) == 0) ? 0 : (((vv & 2) == 0) ? 1 : 2);  // 0=i32 1=u8 2=f32

  // ---- ph0: masks / x0 / any_real -----------------------------------------
  if (t < 128) {
    const int r = t >> 2, s = t & 3;
    const size_t idx = (row0 + r) * 4 + s;
    bool vb;
    if (mode == 0) vb = ((const int*)valid)[idx] != 0;
    else if (mode == 1) vb = ((const unsigned char*)valid)[idx] != 0;
    else vb = ((const float*)valid)[idx] != 0.f;
    s_sc[r * 12 + s] = vb ? 0.f : -5.f;
    s_x0[t] = log1pf(stal[idx]);
  } else if (t < 160) {
    const int r = t - 128;
    const size_t base = (row0 + r) * 4;
    bool any = false;
    for (int s = 0; s < 4; ++s) {
      bool vb;
      if (mode == 0) vb = ((const int*)valid)[base + s] != 0;
      else if (mode == 1) vb = ((const unsigned char*)valid)[base + s] != 0;
      else vb = ((const float*)valid)[base + s] != 0.f;
      any |= vb;
    }
    s_sc[r * 12 + 6] = any ? 1.f : 0.f;
  }
  barrier_lds();  // B0

  // ---- ph1: per-row score consts + QK gemm; tail: prefetch QK2-B ----------
  {
    const int task = lane >> 3, sub = lane & 7;
    const int r = wv * 4 + (task >> 1);
    const int which = task & 1;
    const float* vecp = which ? (W + OFF_NQ) : (W + OFF_NBK);
    const float* hp = h + (row0 + r) * 256 + sub * 32;
    const float* vp = vecp + sub * 32;
    float acc = 0.f;
#pragma unroll
    for (int j = 0; j < 8; ++j) {
      const float4 hv = ld4(hp + j * 4);
      const float4 vvv = ld4(vp + j * 4);
      acc += hv.x * vvv.x + hv.y * vvv.y + hv.z * vvv.z + hv.w * vvv.w;
    }
    acc += __shfl_xor(acc, 1, 64);
    acc += __shfl_xor(acc, 2, 64);
    acc += __shfl_xor(acc, 4, 64);
    if (sub == 0) s_sc[r * 12 + 4 + which] = acc + W[OFF_SCC + which];
  }
  {
    f32x4 acc[2][2] = {{{0.f,0.f,0.f,0.f},{0.f,0.f,0.f,0.f}},
                       {{0.f,0.f,0.f,0.f},{0.f,0.f,0.f,0.f}}};
#pragma unroll
    for (int kt = 0; kt < 8; ++kt) {
      const bf16x8 a0 = ldHfrag(h, row0 + l16, kt * 32 + g * 8);
      const bf16x8 a1 = ldHfrag(h, row0 + 16 + l16, kt * 32 + g * 8);
#pragma unroll
      for (int n2 = 0; n2 < 2; ++n2) {
        const int nt = wv * 2 + n2;
        const bf16x8 b = ldB8(Wu, UOFF_QK + (size_t)((nt * 8 + kt) * 64 + lane) * 8);
        acc[0][n2] = mfma16(a0, b, acc[0][n2]);
        acc[1][n2] = mfma16(a1, b, acc[1][n2]);
      }
    }
#pragma unroll
    for (int n2 = 0; n2 < 2; ++n2) {
      const int col = (wv * 2 + n2) * 16 + l16;
      const float bqk = W[OFF_BQK + col];
#pragma unroll
      for (int mt = 0; mt < 2; ++mt)
#pragma unroll
        for (int reg = 0; reg < 4; ++reg)
          stBF(su, SH_QK, 256, mt * 16 + g * 4 + reg, col, acc[mt][n2][reg] + bqk);
    }
  }
  // early-issue: QK2 B-fragments for kt 0..3 (consumed after B1)
  bf16x8 Bq2[8];
  {
    const int ntp = (wv & 3) * 2;
#pragma unroll
    for (int i = 0; i < 8; ++i) {
      const int kt = i >> 1, n2 = i & 1;
      Bq2[i] = ldB8(Wu, UOFF_QK2 + (size_t)(((ntp + n2) * 8 + kt) * 64 + lane) * 8);
    }
  }
  barrier_lds();  // B1

  // ---- ph2 (merged): QK2 gemm + X2 gemm; tail: prefetch obs rr=0,1 --------
  u16x4 x2p[8];       // x2[r=wv*4+g][s][col=nt*16+l16], retained to ph4
  float4 ob01[8];     // obs rows rr=0,1 prefetch
  {
    const int mt = wv >> 2, ntp = (wv & 3) * 2;
    f32x4 acc2[2] = {{0.f, 0.f, 0.f, 0.f}, {0.f, 0.f, 0.f, 0.f}};
#pragma unroll
    for (int kt = 0; kt < 8; ++kt) {
      const bf16x8 a = ldA8g(su, SH_QK, 256, mt * 16 + l16, kt * 32 + g * 8);
#pragma unroll
      for (int n2 = 0; n2 < 2; ++n2) {
        bf16x8 b;
        if (kt < 4) b = Bq2[kt * 2 + n2];
        else b = ldB8(Wu, UOFF_QK2 + (size_t)(((ntp + n2) * 8 + kt) * 64 + lane) * 8);
        acc2[n2] = mfma16(a, b, acc2[n2]);
      }
    }
    // X2 gemm (on-the-fly A from x0)
    f32x4 accx[8] = {{0.f,0.f,0.f,0.f},{0.f,0.f,0.f,0.f},{0.f,0.f,0.f,0.f},{0.f,0.f,0.f,0.f},
                     {0.f,0.f,0.f,0.f},{0.f,0.f,0.f,0.f},{0.f,0.f,0.f,0.f},{0.f,0.f,0.f,0.f}};
    const float x0v = s_x0[wv * 16 + l16];
#pragma unroll
    for (int kt = 0; kt < 4; ++kt) {
      const int k0 = kt * 32 + g * 8;
      const float4 wa = ld4(w0 + k0), wb = ld4(w0 + k0 + 4);
      const float4 ba = ld4(b0 + k0), bb = ld4(b0 + k0 + 4);
      bf16x8 a;
      a[0] = (__bf16)fmaxf(fmaf(wa.x, x0v, ba.x), 0.f);
      a[1] = (__bf16)fmaxf(fmaf(wa.y, x0v, ba.y), 0.f);
      a[2] = (__bf16)fmaxf(fmaf(wa.z, x0v, ba.z), 0.f);
      a[3] = (__bf16)fmaxf(fmaf(wa.w, x0v, ba.w), 0.f);
      a[4] = (__bf16)fmaxf(fmaf(wb.x, x0v, bb.x), 0.f);
      a[5] = (__bf16)fmaxf(fmaf(wb.y, x0v, bb.y), 0.f);
      a[6] = (__bf16)fmaxf(fmaf(wb.z, x0v, bb.z), 0.f);
      a[7] = (__bf16)fmaxf(fmaf(wb.w, x0v, bb.w), 0.f);
#pragma unroll
      for (int nt = 0; nt < 8; ++nt) {
        const bf16x8 b = ldB8(Wu, UOFF_X2W + (size_t)((nt * 4 + kt) * 64 + lane) * 8);
        accx[nt] = mfma16(a, b, accx[nt]);
      }
    }
    // early-issue obs rows rr=0,1 (HBM; issued after all L2 loads of this phase)
#pragma unroll
    for (int s = 0; s < 4; ++s) {
      ob01[s]     = ld4(obs + ((row0 + wv * 4 + 0) * 4 + s) * 256 + lane * 4);
      ob01[4 + s] = ld4(obs + ((row0 + wv * 4 + 1) * 4 + s) * 256 + lane * 4);
    }
    // epilogues: qk2 -> LDS (unswz); x2 -> regs
#pragma unroll
    for (int n2 = 0; n2 < 2; ++n2) {
      const int col = (ntp + n2) * 16 + l16;
#pragma unroll
      for (int reg = 0; reg < 4; ++reg)
        su[SH_QK2 + (mt * 16 + g * 4 + reg) * 128 + col] = f2bf(acc2[n2][reg]);
    }
#pragma unroll
    for (int nt = 0; nt < 8; ++nt) {
      const int col = nt * 16 + l16;
      const float b1c = b1[col];
      u16x4 xp;
#pragma unroll
      for (int reg = 0; reg < 4; ++reg) xp[reg] = f2bf(fmaxf(accx[nt][reg] + b1c, 0.f));
      x2p[nt] = xp;
    }
  }
  barrier_lds();  // B2

  // ---- ph4: obs rr=2,3 issue; e_rs; scores/softmax; obar,x2b; V prefetch --
  bf16x8 Vb[8];
  {
    float4 ov2[4], ov3[4];
#pragma unroll
    for (int s = 0; s < 4; ++s) {
      ov2[s] = ld4(obs + ((row0 + wv * 4 + 2) * 4 + s) * 256 + lane * 4);
      ov3[s] = ld4(obs + ((row0 + wv * 4 + 3) * 4 + s) * 256 + lane * 4);
    }
    // e_rs for own row r=wv*4+g (q2 rows safe post-B2)
    float ep0 = 0.f, ep1 = 0.f, ep2 = 0.f, ep3 = 0.f;
    const int r_own = wv * 4 + g;
#pragma unroll
    for (int nt = 0; nt < 8; ++nt) {
      const float q2v = bf2f(su[SH_QK2 + r_own * 128 + nt * 16 + l16]);
      ep0 = fmaf(bf2f(x2p[nt][0]), q2v, ep0);
      ep1 = fmaf(bf2f(x2p[nt][1]), q2v, ep1);
      ep2 = fmaf(bf2f(x2p[nt][2]), q2v, ep2);
      ep3 = fmaf(bf2f(x2p[nt][3]), q2v, ep3);
    }
#pragma unroll
    for (int sh = 1; sh <= 8; sh <<= 1) {
      ep0 += __shfl_xor(ep0, sh, 64);
      ep1 += __shfl_xor(ep1, sh, 64);
      ep2 += __shfl_xor(ep2, sh, 64);
      ep3 += __shfl_xor(ep3, sh, 64);
    }
    float px0 = 0.f, px1 = 0.f, px2 = 0.f, px3 = 0.f;
#pragma unroll
    for (int rr = 0; rr < 4; ++rr) {
      const int r = wv * 4 + rr;
      float4 ov[4];
      if (rr == 0) { ov[0] = ob01[0]; ov[1] = ob01[1]; ov[2] = ob01[2]; ov[3] = ob01[3]; }
      else if (rr == 1) { ov[0] = ob01[4]; ov[1] = ob01[5]; ov[2] = ob01[6]; ov[3] = ob01[7]; }
      else if (rr == 2) { ov[0] = ov2[0]; ov[1] = ov2[1]; ov[2] = ov2[2]; ov[3] = ov2[3]; }
      else { ov[0] = ov3[0]; ov[1] = ov3[1]; ov[2] = ov3[2]; ov[3] = ov3[3]; }
      const int qoff = (r * 256 + lane * 4) ^ ((r & 7) << 3);
      const u16x4 qv4 = *reinterpret_cast<const u16x4*>(su + SH_QK + qoff);
      const float q0 = bf2f(qv4[0]), q1 = bf2f(qv4[1]), q2 = bf2f(qv4[2]), q3 = bf2f(qv4[3]);
      const float sbk = s_sc[r * 12 + 4];
      // e broadcast from group rr (all its lanes hold the reduced value)
      const float e0 = __shfl(ep0, rr << 4, 64);
      const float e1 = __shfl(ep1, rr << 4, 64);
      const float e2 = __shfl(ep2, rr << 4, 64);
      const float e3 = __shfl(ep3, rr << 4, 64);
      float sc[4];
#pragma unroll
      for (int s = 0; s < 4; ++s)
        sc[s] = q0 * ov[s].x + q1 * ov[s].y + q2 * ov[s].z + q3 * ov[s].w;
#pragma unroll
      for (int sh = 1; sh <= 32; sh <<= 1) {
#pragma unroll
        for (int s = 0; s < 4; ++s) sc[s] += __shfl_xor(sc[s], sh, 64);
      }
      sc[0] = (sc[0] + e0 + sbk) * 0.0625f + s_sc[r * 12 + 0];
      sc[1] = (sc[1] + e1 + sbk) * 0.0625f + s_sc[r * 12 + 1];
      sc[2] = (sc[2] + e2 + sbk) * 0.0625f + s_sc[r * 12 + 2];
      sc[3] = (sc[3] + e3 + sbk) * 0.0625f + s_sc[r * 12 + 3];
      const float snv = s_sc[r * 12 + 5] * 0.0625f;
      const float m = fmaxf(fmaxf(fmaxf(sc[0], sc[1]), fmaxf(sc[2], sc[3])), snv);
      const float p0e = __expf(sc[0] - m), p1e = __expf(sc[1] - m);
      const float p2e = __expf(sc[2] - m), p3e = __expf(sc[3] - m);
      const float pne = __expf(snv - m);
      const float invD = 1.f / (p0e + p1e + p2e + p3e + pne);
      const float p0 = p0e * invD, p1 = p1e * invD, p2 = p2e * invD, p3 = p3e * invD;
      const int ooff = (r * 256 + lane * 4) ^ ((r & 7) << 3);
      u16x4 o4;
      o4[0] = f2bf(p0 * ov[0].x + p1 * ov[1].x + p2 * ov[2].x + p3 * ov[3].x);
      o4[1] = f2bf(p0 * ov[0].y + p1 * ov[1].y + p2 * ov[2].y + p3 * ov[3].y);
      o4[2] = f2bf(p0 * ov[0].z + p1 * ov[1].z + p2 * ov[2].z + p3 * ov[3].z);
      o4[3] = f2bf(p0 * ov[0].w + p1 * ov[1].w + p2 * ov[2].w + p3 * ov[3].w);
      *reinterpret_cast<u16x4*>(su + SH_OB + ooff) = o4;
      if (lane == 0) s_sc[r * 12 + 7] = pne * invD;  // w4
      px0 = (rr == g) ? p0 : px0;
      px1 = (rr == g) ? p1 : px1;
      px2 = (rr == g) ? p2 : px2;
      px3 = (rr == g) ? p3 : px3;
    }
    // x2b into own (wave-private) SH_QK2 row, swizzled for ph5 A-reads
    {
      const int r = wv * 4 + g;
#pragma unroll
      for (int nt = 0; nt < 8; ++nt) {
        const int col = nt * 16 + l16;
        const float v = px0 * bf2f(x2p[nt][0]) + px1 * bf2f(x2p[nt][1]) +
                        px2 * bf2f(x2p[nt][2]) + px3 * bf2f(x2p[nt][3]);
        su[SH_QK2 + ((r * 128 + col) ^ ((r & 7) << 3))] = f2bf(v);
      }
    }
    // early-issue V B-fragments kt 0..3 (consumed after B3)
#pragma unroll
    for (int i = 0; i < 8; ++i) {
      const int kt = i >> 1, n2 = i & 1;
      Vb[i] = ldB8(Wu, UOFF_V + (size_t)(((wv * 2 + n2) * 8 + kt) * 64 + lane) * 8);
    }
  }
  barrier_lds();  // B3

  // ---- ph5: fused = V(obar) + V2(x2b) + (1-w4)*vb2p + w4*nv; G prefetch ---
  bf16x8 Gb[8];
  {
    f32x4 acc[2][2] = {{{0.f,0.f,0.f,0.f},{0.f,0.f,0.f,0.f}},
                       {{0.f,0.f,0.f,0.f},{0.f,0.f,0.f,0.f}}};
#pragma unroll
    for (int kt = 0; kt < 8; ++kt) {
      const bf16x8 a0 = ldA8g(su, SH_OB, 256, l16, kt * 32 + g * 8);
      const bf16x8 a1 = ldA8g(su, SH_OB, 256, 16 + l16, kt * 32 + g * 8);
#pragma unroll
      for (int n2 = 0; n2 < 2; ++n2) {
        const int nt = wv * 2 + n2;
        bf16x8 b;
        if (kt < 4) b = Vb[kt * 2 + n2];
        else b = ldB8(Wu, UOFF_V + (size_t)((nt * 8 + kt) * 64 + lane) * 8);
        acc[0][n2] = mfma16(a0, b, acc[0][n2]);
        acc[1][n2] = mfma16(a1, b, acc[1][n2]);
      }
    }
#pragma unroll
    for (int kt = 0; kt < 4; ++kt) {
      const bf16x8 a0 = ldA8g(su, SH_QK2, 128, l16, kt * 32 + g * 8);
      const bf16x8 a1 = ldA8g(su, SH_QK2, 128, 16 + l16, kt * 32 + g * 8);
#pragma unroll
      for (int n2 = 0; n2 < 2; ++n2) {
        const int nt = wv * 2 + n2;
        const bf16x8 b = ldB8(Wu, UOFF_V2 + (size_t)((nt * 4 + kt) * 64 + lane) * 8);
        acc[0][n2] = mfma16(a0, b, acc[0][n2]);
        acc[1][n2] = mfma16(a1, b, acc[1][n2]);
      }
    }
    // early-issue G B-fragments kt 0..3 (consumed after B4)
#pragma unroll
    for (int i = 0; i < 8; ++i) {
      const int kt = i >> 1, n2 = i & 1;
      Gb[i] = ldB8(Wu, UOFF_G + (size_t)(((wv * 2 + n2) * 16 + kt) * 64 + lane) * 8);
    }
#pragma unroll
    for (int n2 = 0; n2 < 2; ++n2) {
      const int col = (wv * 2 + n2) * 16 + l16;
      const float vb = W[OFF_VB2P + col];
      const float nvc = nv[col];
#pragma unroll
      for (int mt = 0; mt < 2; ++mt)
#pragma unroll
        for (int reg = 0; reg < 4; ++reg) {
          const int row = mt * 16 + g * 4 + reg;
          const float w4v = s_sc[row * 12 + 7];
          const float f = acc[mt][n2][reg] + (1.f - w4v) * vb + w4v * nvc;
          stBF(su, SH_QK, 256, row, col, f);
        }
    }
  }
  barrier_lds();  // B4

  // ---- ph6: LN stats + gate gemm ------------------------------------------
  {
#pragma unroll
    for (int rr = 0; rr < 4; ++rr) {
      const int r = wv * 4 + rr;
      const int foff = (r * 256 + lane * 4) ^ ((r & 7) << 3);
      const u16x4 f4 = *reinterpret_cast<const u16x4*>(su + SH_QK + foff);
      const float f0 = bf2f(f4[0]), f1 = bf2f(f4[1]), f2v = bf2f(f4[2]), f3 = bf2f(f4[3]);
      float sum = f0 + f1 + f2v + f3;
      float sq = f0 * f0 + f1 * f1 + f2v * f2v + f3 * f3;
#pragma unroll
      for (int sh = 1; sh <= 32; sh <<= 1) {
        sum += __shfl_xor(sum, sh, 64);
        sq += __shfl_xor(sq, sh, 64);
      }
      if (lane == 0) {
        const float mu = sum * (1.f / 256.f);
        const float var = sq * (1.f / 256.f) - mu * mu;
        s_sc[r * 12 + 8] = mu;
        s_sc[r * 12 + 9] = rsqrtf(var + 1e-5f);
      }
    }
  }
  {
    f32x4 acc[2][2] = {{{0.f,0.f,0.f,0.f},{0.f,0.f,0.f,0.f}},
                       {{0.f,0.f,0.f,0.f},{0.f,0.f,0.f,0.f}}};
#pragma unroll
    for (int kt = 0; kt < 8; ++kt) {
      const bf16x8 a0 = ldHfrag(h, row0 + l16, kt * 32 + g * 8);
      const bf16x8 a1 = ldHfrag(h, row0 + 16 + l16, kt * 32 + g * 8);
#pragma unroll
      for (int n2 = 0; n2 < 2; ++n2) {
        const int nt = wv * 2 + n2;
        bf16x8 b;
        if (kt < 4) b = Gb[kt * 2 + n2];
        else b = ldB8(Wu, UOFF_G + (size_t)((nt * 16 + kt) * 64 + lane) * 8);
        acc[0][n2] = mfma16(a0, b, acc[0][n2]);
        acc[1][n2] = mfma16(a1, b, acc[1][n2]);
      }
    }
#pragma unroll
    for (int kt = 8; kt < 16; ++kt) {
      const bf16x8 a0 = ldA8g(su, SH_QK, 256, l16, (kt - 8) * 32 + g * 8);
      const bf16x8 a1 = ldA8g(su, SH_QK, 256, 16 + l16, (kt - 8) * 32 + g * 8);
#pragma unroll
      for (int n2 = 0; n2 < 2; ++n2) {
        const int nt = wv * 2 + n2;
        const bf16x8 b = ldB8(Wu, UOFF_G + (size_t)((nt * 16 + kt) * 64 + lane) * 8);
        acc[0][n2] = mfma16(a0, b, acc[0][n2]);
        acc[1][n2] = mfma16(a1, b, acc[1][n2]);
      }
    }
#pragma unroll
    for (int n2 = 0; n2 < 2; ++n2) {
      const int col = (wv * 2 + n2) * 16 + l16;
      const float bgc = bg[col];
#pragma unroll
      for (int mt = 0; mt < 2; ++mt)
#pragma unroll
        for (int reg = 0; reg < 4; ++reg) {
          const int row = mt * 16 + g * 4 + reg;
          const float z = acc[mt][n2][reg] + bgc;
          su[SH_OB + row * 256 + col] = f2bf(1.f / (1.f + __expf(-z)));
        }
    }
  }
  barrier_lds();  // B5

  // ---- ph7: out = h + gate*any_real*((fused-mu)*rstd*lnw+lnb) -------------
  {
    const int half = t >> 8, col = t & 255;
    const float lw = lnw[col], lb = lnb[col];
#pragma unroll
    for (int i = 0; i < 16; ++i) {
      const int r = i * 2 + half;
      const float mu = s_sc[r * 12 + 8], inv = s_sc[r * 12 + 9], ar = s_sc[r * 12 + 6];
      const float f = bf2f(su[SH_QK + ((r * 256 + col) ^ ((r & 7) << 3))]);
      const float gt = bf2f(su[SH_OB + r * 256 + col]) * ar;
      const float upd = (f - mu) * inv * lw + lb;
      out[(row0 + r) * 256 + col] = h[(row0 + r) * 256 + col] + gt * upd;
    }
  }
}

extern "C" void kernel_launch(void* const* d_in, const int* in_sizes, int n_in, void* d_out,
                              int out_size, void* d_ws, size_t ws_size, hipStream_t stream) {
  const float* h = (const float*)d_in[0];
  const float* obs = (const float*)d_in[1];
  const float* st = (const float*)d_in[2];
  const void* vd = d_in[3];
  const float* Wq = (const float*)d_in[4];
  const float* bq = (const float*)d_in[5];
  const float* Wk = (const float*)d_in[6];
  const float* bk = (const float*)d_in[7];
  const float* Wv = (const float*)d_in[8];
  const float* bv = (const float*)d_in[9];
  const float* nk = (const float*)d_in[10];
  const float* nv = (const float*)d_in[11];
  const float* w0 = (const float*)d_in[12];
  const float* b0 = (const float*)d_in[13];
  const float* w1 = (const float*)d_in[14];
  const float* b1 = (const float*)d_in[15];
  const float* w2 = (const float*)d_in[16];
  const float* b2 = (const float*)d_in[17];
  const float* Wg = (const float*)d_in[18];
  const float* bg = (const float*)d_in[19];
  const float* lnw = (const float*)d_in[20];
  const float* lnb = (const float*)d_in[21];
  float* out = (float*)d_out;
  float* W = (float*)d_ws;
  const int L = in_sizes[0] / 256;

  k_zero<<<1, 64, 0, stream>>>((int*)d_ws);
  k_flag<<<256, 256, 0, stream>>>((const unsigned int*)vd, L, (int*)d_ws);
  k_prep<<<673, 256, 0, stream>>>(Wq, bq, Wk, bk, Wv, bv, nk, w1, w2, b2, Wg, W);
  k_main<<<L / Tr, 512, 0, stream>>>(h, obs, st, vd, w0, b0, b1, bg, lnw, lnb, nv, W,
                                     (const int*)d_ws, out);
}

// Round 13
// 374.278 us; speedup vs baseline: 1.2725x; 1.0016x over previous
//
#include <hip/hip_runtime.h>
#include <math.h>

// ---------------------------------------------------------------------------
// ObservationFusionModule — round 13: FINAL = R11 restored (passing, 375us).
// R12's (512,4) failed correctness: 128-reg cap < true unified VGPR+AGPR
// usage (~160-192/wave) -> forced spill/rebalance corruption. That confirms
// the session invariant: 1 resident 8-wave block/CU is register-structural
// (2 waves/EU at ~192 regs). All levers tested (R3/R5-R12); latency-bound
// plateau at ~363us k_main is the practical ceiling for this structure.
// ---------------------------------------------------------------------------

typedef __bf16 bf16x8 __attribute__((ext_vector_type(8)));
typedef float f32x4 __attribute__((ext_vector_type(4)));
typedef unsigned short u16;
typedef unsigned short u16x4 __attribute__((ext_vector_type(4)));

constexpr int Tr = 32;  // rows per block (8 waves x 4 rows)

// ws float offsets (W[0] = valid-dtype flag)
constexpr int OFF_BQK = 16;    // [256] Wk^T bq
constexpr int OFF_NBK = 272;   // [256] Wq^T (bk + Wk b2)
constexpr int OFF_NQ  = 528;   // [256] Wq^T null_key
constexpr int OFF_VB2P = 784;  // [256] Wv b2 + bv
constexpr int OFF_SCC = 1040;  // [0]=bq.(bk+Wk b2) [1]=bq.nk
// bf16 fragment region at W+2048 floats; [nt][kt][64][8] ushorts each
constexpr size_t UOFF_QK  = 0;       // 16x8
constexpr size_t UOFF_X2W = 65536;   // 8x4
constexpr size_t UOFF_QK2 = 81920;   // 8x8
constexpr size_t UOFF_V   = 114688;  // 16x8
constexpr size_t UOFF_V2  = 180224;  // 16x4
constexpr size_t UOFF_G   = 212992;  // 16x16

// shared layout (ushort units)
constexpr int SH_QK  = 0;      // [32][256] swz: qk ph1-ph4, fused ph5-ph7
constexpr int SH_QK2 = 8192;   // [32][128]: qk2 unswz ph2->ph4; x2b swz ph4->ph5
constexpr int SH_OB  = 12288;  // [32][256]: obar swz ph4->ph5; gate unswz ph6->ph7

__device__ __forceinline__ float4 ld4(const float* p) { return *reinterpret_cast<const float4*>(p); }
__device__ __forceinline__ u16 f2bf(float x) { __bf16 b = (__bf16)x; return __builtin_bit_cast(u16, b); }
__device__ __forceinline__ float bf2f(u16 u) {
  unsigned v = ((unsigned)u) << 16;
  return __builtin_bit_cast(float, v);
}
__device__ __forceinline__ f32x4 mfma16(bf16x8 a, bf16x8 b, f32x4 c) {
  return __builtin_amdgcn_mfma_f32_16x16x32_bf16(a, b, c, 0, 0, 0);
}
__device__ __forceinline__ bf16x8 ldA8g(const u16* su, int base, int stride, int row, int kcol) {
  int off = (row * stride + kcol) ^ ((row & 7) << 3);
  return *reinterpret_cast<const bf16x8*>(su + base + off);
}
__device__ __forceinline__ bf16x8 ldB8(const u16* p, size_t off) {
  return *reinterpret_cast<const bf16x8*>(p + off);
}
__device__ __forceinline__ void stBF(u16* su, int base, int stride, int row, int col, float v) {
  int off = (row * stride + col) ^ ((row & 7) << 3);
  su[base + off] = f2bf(v);
}
__device__ __forceinline__ bf16x8 ldHfrag(const float* __restrict__ h, size_t row, int k) {
  const float4 a = ld4(h + row * 256 + k);
  const float4 b = ld4(h + row * 256 + k + 4);
  bf16x8 r;
  r[0] = (__bf16)a.x; r[1] = (__bf16)a.y; r[2] = (__bf16)a.z; r[3] = (__bf16)a.w;
  r[4] = (__bf16)b.x; r[5] = (__bf16)b.y; r[6] = (__bf16)b.z; r[7] = (__bf16)b.w;
  return r;
}
// LDS-only barrier: vmcnt NOT drained (register-destined global loads ride across)
__device__ __forceinline__ void barrier_lds() {
  asm volatile("s_waitcnt lgkmcnt(0)" ::: "memory");
  __builtin_amdgcn_s_barrier();
  asm volatile("" ::: "memory");
}

// --- valid_stack dtype probe ------------------------------------------------
__global__ void k_zero(int* __restrict__ f) {
  if (threadIdx.x == 0) f[0] = 0;
}
__global__ void k_flag(const unsigned int* __restrict__ v, int nwords, int* __restrict__ flag_out) {
  int my = 0;
  for (int i = blockIdx.x * blockDim.x + threadIdx.x; i < nwords; i += gridDim.x * blockDim.x) {
    const unsigned int w = v[i];
    if (w > 1u) my |= 1;
    if (((w & 0xFFu) > 1u) || (((w >> 8) & 0xFFu) > 1u) || (((w >> 16) & 0xFFu) > 1u) ||
        ((w >> 24) > 1u))
      my |= 2;
  }
  my |= __shfl_xor(my, 32, 64);
  my |= __shfl_xor(my, 16, 64);
  my |= __shfl_xor(my, 8, 64);
  my |= __shfl_xor(my, 4, 64);
  my |= __shfl_xor(my, 2, 64);
  my |= __shfl_xor(my, 1, 64);
  if ((threadIdx.x & 63) == 0 && my) atomicOr(flag_out, my);
}

// --- weight prep (unchanged, passing since R3) ------------------------------
__global__ void k_prep(const float* __restrict__ Wq, const float* __restrict__ bq,
                       const float* __restrict__ Wk, const float* __restrict__ bk,
                       const float* __restrict__ Wv, const float* __restrict__ bv,
                       const float* __restrict__ nk, const float* __restrict__ w1,
                       const float* __restrict__ w2, const float* __restrict__ b2,
                       const float* __restrict__ Wg, float* __restrict__ W) {
  const int b = blockIdx.x, t = threadIdx.x;
  u16* Wu = (u16*)(W + 2048);
  __shared__ float s_tile[48 * 260];
  if (b < 672) {
    int gemm, nt, kt, KT;
    size_t ubase;
    if (b < 128)      { gemm = 0; KT = 8;  kt = b & 7;          nt = b >> 3;          ubase = UOFF_QK; }
    else if (b < 160) { gemm = 1; KT = 4;  kt = (b - 128) & 3;  nt = (b - 128) >> 2;  ubase = UOFF_X2W; }
    else if (b < 224) { gemm = 2; KT = 8;  kt = (b - 160) & 7;  nt = (b - 160) >> 3;  ubase = UOFF_QK2; }
    else if (b < 352) { gemm = 3; KT = 8;  kt = (b - 224) & 7;  nt = (b - 224) >> 3;  ubase = UOFF_V; }
    else if (b < 416) { gemm = 4; KT = 4;  kt = (b - 352) & 3;  nt = (b - 352) >> 2;  ubase = UOFF_V2; }
    else              { gemm = 5; KT = 16; kt = (b - 416) & 15; nt = (b - 416) >> 4;  ubase = UOFF_G; }
    if (gemm == 0 || gemm == 4) {
      float* sA = s_tile;             // [16][260]
      float* sB = s_tile + 16 * 260;  // [32][260]
      const int n0 = nt * 16, k0 = kt * 32;
      if (gemm == 0) {
        for (int idx = t; idx < 4096; idx += 256) {
          const int o = idx >> 4, n = idx & 15;
          sA[n * 260 + o] = Wk[o * 256 + n0 + n];
        }
        for (int idx = t; idx < 8192; idx += 256) {
          const int o = idx >> 5, k = idx & 31;
          sB[k * 260 + o] = Wq[o * 256 + k0 + k];
        }
      } else {
        for (int idx = t; idx < 4096; idx += 256) {
          const int n = idx >> 8, o = idx & 255;
          sA[n * 260 + o] = Wv[(size_t)(n0 + n) * 256 + o];
        }
        for (int idx = t; idx < 8192; idx += 256) {
          const int o = idx >> 5, k = idx & 31;
          sB[k * 260 + o] = w2[o * 128 + k0 + k];
        }
      }
      __syncthreads();
      for (int e = t; e < 512; e += 256) {
        const int l = e >> 3, j = e & 7;
        const int n = l & 15;
        const int k = ((l >> 4) << 3) + j;
        const float4* pa = (const float4*)(sA + n * 260);
        const float4* pb = (const float4*)(sB + k * 260);
        float acc = 0.f;
#pragma unroll 8
        for (int o4 = 0; o4 < 64; ++o4) {
          const float4 a = pa[o4], bb = pb[o4];
          acc += a.x * bb.x + a.y * bb.y + a.z * bb.z + a.w * bb.w;
        }
        Wu[ubase + (size_t)(nt * KT + kt) * 512 + e] = f2bf(acc);
      }
    } else {
      for (int e = t; e < 512; e += 256) {
        const int l = e >> 3, j = e & 7;
        const int n = nt * 16 + (l & 15);
        const int k = kt * 32 + ((l >> 4) << 3) + j;
        float val;
        if (gemm == 1)      val = w1[n * 128 + k];
        else if (gemm == 2) val = w2[k * 128 + n];
        else if (gemm == 3) val = Wv[n * 256 + k];
        else                val = Wg[n * 512 + k];
        Wu[ubase + (size_t)(nt * KT + kt) * 512 + e] = f2bf(val);
      }
    }
  } else {  // vectors + scalars
    float* s_u = s_tile;
    float a = 0.f;
    for (int hh = 0; hh < 256; ++hh) a = fmaf(Wk[t * 256 + hh], b2[hh], a);
    s_u[t] = a + bk[t];
    __syncthreads();
    float a1 = 0.f, a2 = 0.f, a3 = 0.f, a4 = 0.f;
    for (int o = 0; o < 256; ++o) {
      a1 = fmaf(Wq[o * 256 + t], s_u[o], a1);
      a2 = fmaf(Wq[o * 256 + t], nk[o], a2);
      a3 = fmaf(Wk[o * 256 + t], bq[o], a3);
      a4 = fmaf(Wv[t * 256 + o], b2[o], a4);
    }
    W[OFF_NBK + t] = a1;
    W[OFF_NQ + t] = a2;
    W[OFF_BQK + t] = a3;
    W[OFF_VB2P + t] = a4 + bv[t];
    if (t == 0) {
      float c1 = 0.f, c2 = 0.f;
      for (int o = 0; o < 256; ++o) {
        c1 = fmaf(bq[o], s_u[o], c1);
        c2 = fmaf(bq[o], nk[o], c2);
      }
      W[OFF_SCC] = c1;
      W[OFF_SCC + 1] = c2;
    }
  }
}

// --- main fused kernel (R6 structure, static shared) ------------------------
// s_sc row stride 12: 0-3 mask, 4 sbk, 5 snull, 6 anyreal, 7 w4, 8 mu, 9 rstd
__launch_bounds__(512) __global__
void k_main(const float* __restrict__ h, const float* __restrict__ obs,
            const float* __restrict__ stal, const void* __restrict__ valid,
            const float* __restrict__ w0, const float* __restrict__ b0,
            const float* __restrict__ b1, const float* __restrict__ bg,
            const float* __restrict__ lnw, const float* __restrict__ lnb,
            const float* __restrict__ nv, const float* __restrict__ W,
            const int* __restrict__ flagp, float* __restrict__ out) {
  __shared__ u16 su[20480];     // 40960 B: SH_QK + SH_QK2 + SH_OB
  __shared__ float s_sc[384];   // [32][12]
  __shared__ float s_x0[128];
  const u16* Wu = (const u16*)(W + 2048);
  const int t = threadIdx.x;
  const int lane = t & 63, wv = t >> 6;   // wv 0..7
  const int l16 = lane & 15, g = lane >> 4;
  const size_t row0 = (size_t)blockIdx.x * Tr;
  const int vv = *flagp;
  const int mode = ((vv & 1) == 0) ? 0 : (((vv & 2) == 0) ? 1 : 2);  // 0=i32 1=u8 2=f32

  // ---- ph0: masks / x0 / any_real -----------------------------------------
  if (t < 128) {
    const int r = t >> 2, s = t & 3;
    const size_t idx = (row0 + r) * 4 + s;
    bool vb;
    if (mode == 0) vb = ((const int*)valid)[idx] != 0;
    else if (mode == 1) vb = ((const unsigned char*)valid)[idx] != 0;
    else vb = ((const float*)valid)[idx] != 0.f;
    s_sc[r * 12 + s] = vb ? 0.f : -5.f;
    s_x0[t] = log1pf(stal[idx]);
  } else if (t < 160) {
    const int r = t - 128;
    const size_t base = (row0 + r) * 4;
    bool any = false;
    for (int s = 0; s < 4; ++s) {
      bool vb;
      if (mode == 0) vb = ((const int*)valid)[base + s] != 0;
      else if (mode == 1) vb = ((const unsigned char*)valid)[base + s] != 0;
      else vb = ((const float*)valid)[base + s] != 0.f;
      any |= vb;
    }
    s_sc[r * 12 + 6] = any ? 1.f : 0.f;
  }
  barrier_lds();  // B0

  // ---- ph1: per-row score consts + QK gemm; tail: prefetch QK2-B ----------
  {
    const int task = lane >> 3, sub = lane & 7;
    const int r = wv * 4 + (task >> 1);
    const int which = task & 1;
    const float* vecp = which ? (W + OFF_NQ) : (W + OFF_NBK);
    const float* hp = h + (row0 + r) * 256 + sub * 32;
    const float* vp = vecp + sub * 32;
    float acc = 0.f;
#pragma unroll
    for (int j = 0; j < 8; ++j) {
      const float4 hv = ld4(hp + j * 4);
      const float4 vvv = ld4(vp + j * 4);
      acc += hv.x * vvv.x + hv.y * vvv.y + hv.z * vvv.z + hv.w * vvv.w;
    }
    acc += __shfl_xor(acc, 1, 64);
    acc += __shfl_xor(acc, 2, 64);
    acc += __shfl_xor(acc, 4, 64);
    if (sub == 0) s_sc[r * 12 + 4 + which] = acc + W[OFF_SCC + which];
  }
  {
    f32x4 acc[2][2] = {{{0.f,0.f,0.f,0.f},{0.f,0.f,0.f,0.f}},
                       {{0.f,0.f,0.f,0.f},{0.f,0.f,0.f,0.f}}};
#pragma unroll
    for (int kt = 0; kt < 8; ++kt) {
      const bf16x8 a0 = ldHfrag(h, row0 + l16, kt * 32 + g * 8);
      const bf16x8 a1 = ldHfrag(h, row0 + 16 + l16, kt * 32 + g * 8);
#pragma unroll
      for (int n2 = 0; n2 < 2; ++n2) {
        const int nt = wv * 2 + n2;
        const bf16x8 b = ldB8(Wu, UOFF_QK + (size_t)((nt * 8 + kt) * 64 + lane) * 8);
        acc[0][n2] = mfma16(a0, b, acc[0][n2]);
        acc[1][n2] = mfma16(a1, b, acc[1][n2]);
      }
    }
#pragma unroll
    for (int n2 = 0; n2 < 2; ++n2) {
      const int col = (wv * 2 + n2) * 16 + l16;
      const float bqk = W[OFF_BQK + col];
#pragma unroll
      for (int mt = 0; mt < 2; ++mt)
#pragma unroll
        for (int reg = 0; reg < 4; ++reg)
          stBF(su, SH_QK, 256, mt * 16 + g * 4 + reg, col, acc[mt][n2][reg] + bqk);
    }
  }
  // early-issue: QK2 B-fragments for kt 0..3 (consumed after B1)
  bf16x8 Bq2[8];
  {
    const int ntp = (wv & 3) * 2;
#pragma unroll
    for (int i = 0; i < 8; ++i) {
      const int kt = i >> 1, n2 = i & 1;
      Bq2[i] = ldB8(Wu, UOFF_QK2 + (size_t)(((ntp + n2) * 8 + kt) * 64 + lane) * 8);
    }
  }
  barrier_lds();  // B1

  // ---- ph2 (merged): QK2 gemm + X2 gemm; tail: prefetch obs rr=0,1 --------
  u16x4 x2p[8];       // x2[r=wv*4+g][s][col=nt*16+l16], retained to ph4
  float4 ob01[8];     // obs rows rr=0,1 prefetch
  {
    const int mt = wv >> 2, ntp = (wv & 3) * 2;
    f32x4 acc2[2] = {{0.f, 0.f, 0.f, 0.f}, {0.f, 0.f, 0.f, 0.f}};
#pragma unroll
    for (int kt = 0; kt < 8; ++kt) {
      const bf16x8 a = ldA8g(su, SH_QK, 256, mt * 16 + l16, kt * 32 + g * 8);
#pragma unroll
      for (int n2 = 0; n2 < 2; ++n2) {
        bf16x8 b;
        if (kt < 4) b = Bq2[kt * 2 + n2];
        else b = ldB8(Wu, UOFF_QK2 + (size_t)(((ntp + n2) * 8 + kt) * 64 + lane) * 8);
        acc2[n2] = mfma16(a, b, acc2[n2]);
      }
    }
    // X2 gemm (on-the-fly A from x0)
    f32x4 accx[8] = {{0.f,0.f,0.f,0.f},{0.f,0.f,0.f,0.f},{0.f,0.f,0.f,0.f},{0.f,0.f,0.f,0.f},
                     {0.f,0.f,0.f,0.f},{0.f,0.f,0.f,0.f},{0.f,0.f,0.f,0.f},{0.f,0.f,0.f,0.f}};
    const float x0v = s_x0[wv * 16 + l16];
#pragma unroll
    for (int kt = 0; kt < 4; ++kt) {
      const int k0 = kt * 32 + g * 8;
      const float4 wa = ld4(w0 + k0), wb = ld4(w0 + k0 + 4);
      const float4 ba = ld4(b0 + k0), bb = ld4(b0 + k0 + 4);
      bf16x8 a;
      a[0] = (__bf16)fmaxf(fmaf(wa.x, x0v, ba.x), 0.f);
      a[1] = (__bf16)fmaxf(fmaf(wa.y, x0v, ba.y), 0.f);
      a[2] = (__bf16)fmaxf(fmaf(wa.z, x0v, ba.z), 0.f);
      a[3] = (__bf16)fmaxf(fmaf(wa.w, x0v, ba.w), 0.f);
      a[4] = (__bf16)fmaxf(fmaf(wb.x, x0v, bb.x), 0.f);
      a[5] = (__bf16)fmaxf(fmaf(wb.y, x0v, bb.y), 0.f);
      a[6] = (__bf16)fmaxf(fmaf(wb.z, x0v, bb.z), 0.f);
      a[7] = (__bf16)fmaxf(fmaf(wb.w, x0v, bb.w), 0.f);
#pragma unroll
      for (int nt = 0; nt < 8; ++nt) {
        const bf16x8 b = ldB8(Wu, UOFF_X2W + (size_t)((nt * 4 + kt) * 64 + lane) * 8);
        accx[nt] = mfma16(a, b, accx[nt]);
      }
    }
    // early-issue obs rows rr=0,1 (HBM; issued after all L2 loads of this phase)
#pragma unroll
    for (int s = 0; s < 4; ++s) {
      ob01[s]     = ld4(obs + ((row0 + wv * 4 + 0) * 4 + s) * 256 + lane * 4);
      ob01[4 + s] = ld4(obs + ((row0 + wv * 4 + 1) * 4 + s) * 256 + lane * 4);
    }
    // epilogues: qk2 -> LDS (unswz); x2 -> regs
#pragma unroll
    for (int n2 = 0; n2 < 2; ++n2) {
      const int col = (ntp + n2) * 16 + l16;
#pragma unroll
      for (int reg = 0; reg < 4; ++reg)
        su[SH_QK2 + (mt * 16 + g * 4 + reg) * 128 + col] = f2bf(acc2[n2][reg]);
    }
#pragma unroll
    for (int nt = 0; nt < 8; ++nt) {
      const int col = nt * 16 + l16;
      const float b1c = b1[col];
      u16x4 xp;
#pragma unroll
      for (int reg = 0; reg < 4; ++reg) xp[reg] = f2bf(fmaxf(accx[nt][reg] + b1c, 0.f));
      x2p[nt] = xp;
    }
  }
  barrier_lds();  // B2

  // ---- ph4: obs rr=2,3 issue; e_rs; scores/softmax; obar,x2b; V prefetch --
  bf16x8 Vb[8];
  {
    float4 ov2[4], ov3[4];
#pragma unroll
    for (int s = 0; s < 4; ++s) {
      ov2[s] = ld4(obs + ((row0 + wv * 4 + 2) * 4 + s) * 256 + lane * 4);
      ov3[s] = ld4(obs + ((row0 + wv * 4 + 3) * 4 + s) * 256 + lane * 4);
    }
    // e_rs for own row r=wv*4+g (q2 rows safe post-B2)
    float ep0 = 0.f, ep1 = 0.f, ep2 = 0.f, ep3 = 0.f;
    const int r_own = wv * 4 + g;
#pragma unroll
    for (int nt = 0; nt < 8; ++nt) {
      const float q2v = bf2f(su[SH_QK2 + r_own * 128 + nt * 16 + l16]);
      ep0 = fmaf(bf2f(x2p[nt][0]), q2v, ep0);
      ep1 = fmaf(bf2f(x2p[nt][1]), q2v, ep1);
      ep2 = fmaf(bf2f(x2p[nt][2]), q2v, ep2);
      ep3 = fmaf(bf2f(x2p[nt][3]), q2v, ep3);
    }
#pragma unroll
    for (int sh = 1; sh <= 8; sh <<= 1) {
      ep0 += __shfl_xor(ep0, sh, 64);
      ep1 += __shfl_xor(ep1, sh, 64);
      ep2 += __shfl_xor(ep2, sh, 64);
      ep3 += __shfl_xor(ep3, sh, 64);
    }
    float px0 = 0.f, px1 = 0.f, px2 = 0.f, px3 = 0.f;
#pragma unroll
    for (int rr = 0; rr < 4; ++rr) {
      const int r = wv * 4 + rr;
      float4 ov[4];
      if (rr == 0) { ov[0] = ob01[0]; ov[1] = ob01[1]; ov[2] = ob01[2]; ov[3] = ob01[3]; }
      else if (rr == 1) { ov[0] = ob01[4]; ov[1] = ob01[5]; ov[2] = ob01[6]; ov[3] = ob01[7]; }
      else if (rr == 2) { ov[0] = ov2[0]; ov[1] = ov2[1]; ov[2] = ov2[2]; ov[3] = ov2[3]; }
      else { ov[0] = ov3[0]; ov[1] = ov3[1]; ov[2] = ov3[2]; ov[3] = ov3[3]; }
      const int qoff = (r * 256 + lane * 4) ^ ((r & 7) << 3);
      const u16x4 qv4 = *reinterpret_cast<const u16x4*>(su + SH_QK + qoff);
      const float q0 = bf2f(qv4[0]), q1 = bf2f(qv4[1]), q2 = bf2f(qv4[2]), q3 = bf2f(qv4[3]);
      const float sbk = s_sc[r * 12 + 4];
      // e broadcast from group rr (all its lanes hold the reduced value)
      const float e0 = __shfl(ep0, rr << 4, 64);
      const float e1 = __shfl(ep1, rr << 4, 64);
      const float e2 = __shfl(ep2, rr << 4, 64);
      const float e3 = __shfl(ep3, rr << 4, 64);
      float sc[4];
#pragma unroll
      for (int s = 0; s < 4; ++s)
        sc[s] = q0 * ov[s].x + q1 * ov[s].y + q2 * ov[s].z + q3 * ov[s].w;
#pragma unroll
      for (int sh = 1; sh <= 32; sh <<= 1) {
#pragma unroll
        for (int s = 0; s < 4; ++s) sc[s] += __shfl_xor(sc[s], sh, 64);
      }
      sc[0] = (sc[0] + e0 + sbk) * 0.0625f + s_sc[r * 12 + 0];
      sc[1] = (sc[1] + e1 + sbk) * 0.0625f + s_sc[r * 12 + 1];
      sc[2] = (sc[2] + e2 + sbk) * 0.0625f + s_sc[r * 12 + 2];
      sc[3] = (sc[3] + e3 + sbk) * 0.0625f + s_sc[r * 12 + 3];
      const float snv = s_sc[r * 12 + 5] * 0.0625f;
      const float m = fmaxf(fmaxf(fmaxf(sc[0], sc[1]), fmaxf(sc[2], sc[3])), snv);
      const float p0e = __expf(sc[0] - m), p1e = __expf(sc[1] - m);
      const float p2e = __expf(sc[2] - m), p3e = __expf(sc[3] - m);
      const float pne = __expf(snv - m);
      const float invD = 1.f / (p0e + p1e + p2e + p3e + pne);
      const float p0 = p0e * invD, p1 = p1e * invD, p2 = p2e * invD, p3 = p3e * invD;
      const int ooff = (r * 256 + lane * 4) ^ ((r & 7) << 3);
      u16x4 o4;
      o4[0] = f2bf(p0 * ov[0].x + p1 * ov[1].x + p2 * ov[2].x + p3 * ov[3].x);
      o4[1] = f2bf(p0 * ov[0].y + p1 * ov[1].y + p2 * ov[2].y + p3 * ov[3].y);
      o4[2] = f2bf(p0 * ov[0].z + p1 * ov[1].z + p2 * ov[2].z + p3 * ov[3].z);
      o4[3] = f2bf(p0 * ov[0].w + p1 * ov[1].w + p2 * ov[2].w + p3 * ov[3].w);
      *reinterpret_cast<u16x4*>(su + SH_OB + ooff) = o4;
      if (lane == 0) s_sc[r * 12 + 7] = pne * invD;  // w4
      px0 = (rr == g) ? p0 : px0;
      px1 = (rr == g) ? p1 : px1;
      px2 = (rr == g) ? p2 : px2;
      px3 = (rr == g) ? p3 : px3;
    }
    // x2b into own (wave-private) SH_QK2 row, swizzled for ph5 A-reads
    {
      const int r = wv * 4 + g;
#pragma unroll
      for (int nt = 0; nt < 8; ++nt) {
        const int col = nt * 16 + l16;
        const float v = px0 * bf2f(x2p[nt][0]) + px1 * bf2f(x2p[nt][1]) +
                        px2 * bf2f(x2p[nt][2]) + px3 * bf2f(x2p[nt][3]);
        su[SH_QK2 + ((r * 128 + col) ^ ((r & 7) << 3))] = f2bf(v);
      }
    }
    // early-issue V B-fragments kt 0..3 (consumed after B3)
#pragma unroll
    for (int i = 0; i < 8; ++i) {
      const int kt = i >> 1, n2 = i & 1;
      Vb[i] = ldB8(Wu, UOFF_V + (size_t)(((wv * 2 + n2) * 8 + kt) * 64 + lane) * 8);
    }
  }
  barrier_lds();  // B3

  // ---- ph5: fused = V(obar) + V2(x2b) + (1-w4)*vb2p + w4*nv; G prefetch ---
  bf16x8 Gb[8];
  {
    f32x4 acc[2][2] = {{{0.f,0.f,0.f,0.f},{0.f,0.f,0.f,0.f}},
                       {{0.f,0.f,0.f,0.f},{0.f,0.f,0.f,0.f}}};
#pragma unroll
    for (int kt = 0; kt < 8; ++kt) {
      const bf16x8 a0 = ldA8g(su, SH_OB, 256, l16, kt * 32 + g * 8);
      const bf16x8 a1 = ldA8g(su, SH_OB, 256, 16 + l16, kt * 32 + g * 8);
#pragma unroll
      for (int n2 = 0; n2 < 2; ++n2) {
        const int nt = wv * 2 + n2;
        bf16x8 b;
        if (kt < 4) b = Vb[kt * 2 + n2];
        else b = ldB8(Wu, UOFF_V + (size_t)((nt * 8 + kt) * 64 + lane) * 8);
        acc[0][n2] = mfma16(a0, b, acc[0][n2]);
        acc[1][n2] = mfma16(a1, b, acc[1][n2]);
      }
    }
#pragma unroll
    for (int kt = 0; kt < 4; ++kt) {
      const bf16x8 a0 = ldA8g(su, SH_QK2, 128, l16, kt * 32 + g * 8);
      const bf16x8 a1 = ldA8g(su, SH_QK2, 128, 16 + l16, kt * 32 + g * 8);
#pragma unroll
      for (int n2 = 0; n2 < 2; ++n2) {
        const int nt = wv * 2 + n2;
        const bf16x8 b = ldB8(Wu, UOFF_V2 + (size_t)((nt * 4 + kt) * 64 + lane) * 8);
        acc[0][n2] = mfma16(a0, b, acc[0][n2]);
        acc[1][n2] = mfma16(a1, b, acc[1][n2]);
      }
    }
    // early-issue G B-fragments kt 0..3 (consumed after B4)
#pragma unroll
    for (int i = 0; i < 8; ++i) {
      const int kt = i >> 1, n2 = i & 1;
      Gb[i] = ldB8(Wu, UOFF_G + (size_t)(((wv * 2 + n2) * 16 + kt) * 64 + lane) * 8);
    }
#pragma unroll
    for (int n2 = 0; n2 < 2; ++n2) {
      const int col = (wv * 2 + n2) * 16 + l16;
      const float vb = W[OFF_VB2P + col];
      const float nvc = nv[col];
#pragma unroll
      for (int mt = 0; mt < 2; ++mt)
#pragma unroll
        for (int reg = 0; reg < 4; ++reg) {
          const int row = mt * 16 + g * 4 + reg;
          const float w4v = s_sc[row * 12 + 7];
          const float f = acc[mt][n2][reg] + (1.f - w4v) * vb + w4v * nvc;
          stBF(su, SH_QK, 256, row, col, f);
        }
    }
  }
  barrier_lds();  // B4

  // ---- ph6: LN stats + gate gemm ------------------------------------------
  {
#pragma unroll
    for (int rr = 0; rr < 4; ++rr) {
      const int r = wv * 4 + rr;
      const int foff = (r * 256 + lane * 4) ^ ((r & 7) << 3);
      const u16x4 f4 = *reinterpret_cast<const u16x4*>(su + SH_QK + foff);
      const float f0 = bf2f(f4[0]), f1 = bf2f(f4[1]), f2v = bf2f(f4[2]), f3 = bf2f(f4[3]);
      float sum = f0 + f1 + f2v + f3;
      float sq = f0 * f0 + f1 * f1 + f2v * f2v + f3 * f3;
#pragma unroll
      for (int sh = 1; sh <= 32; sh <<= 1) {
        sum += __shfl_xor(sum, sh, 64);
        sq += __shfl_xor(sq, sh, 64);
      }
      if (lane == 0) {
        const float mu = sum * (1.f / 256.f);
        const float var = sq * (1.f / 256.f) - mu * mu;
        s_sc[r * 12 + 8] = mu;
        s_sc[r * 12 + 9] = rsqrtf(var + 1e-5f);
      }
    }
  }
  {
    f32x4 acc[2][2] = {{{0.f,0.f,0.f,0.f},{0.f,0.f,0.f,0.f}},
                       {{0.f,0.f,0.f,0.f},{0.f,0.f,0.f,0.f}}};
#pragma unroll
    for (int kt = 0; kt < 8; ++kt) {
      const bf16x8 a0 = ldHfrag(h, row0 + l16, kt * 32 + g * 8);
      const bf16x8 a1 = ldHfrag(h, row0 + 16 + l16, kt * 32 + g * 8);
#pragma unroll
      for (int n2 = 0; n2 < 2; ++n2) {
        const int nt = wv * 2 + n2;
        bf16x8 b;
        if (kt < 4) b = Gb[kt * 2 + n2];
        else b = ldB8(Wu, UOFF_G + (size_t)((nt * 16 + kt) * 64 + lane) * 8);
        acc[0][n2] = mfma16(a0, b, acc[0][n2]);
        acc[1][n2] = mfma16(a1, b, acc[1][n2]);
      }
    }
#pragma unroll
    for (int kt = 8; kt < 16; ++kt) {
      const bf16x8 a0 = ldA8g(su, SH_QK, 256, l16, (kt - 8) * 32 + g * 8);
      const bf16x8 a1 = ldA8g(su, SH_QK, 256, 16 + l16, (kt - 8) * 32 + g * 8);
#pragma unroll
      for (int n2 = 0; n2 < 2; ++n2) {
        const int nt = wv * 2 + n2;
        const bf16x8 b = ldB8(Wu, UOFF_G + (size_t)((nt * 16 + kt) * 64 + lane) * 8);
        acc[0][n2] = mfma16(a0, b, acc[0][n2]);
        acc[1][n2] = mfma16(a1, b, acc[1][n2]);
      }
    }
#pragma unroll
    for (int n2 = 0; n2 < 2; ++n2) {
      const int col = (wv * 2 + n2) * 16 + l16;
      const float bgc = bg[col];
#pragma unroll
      for (int mt = 0; mt < 2; ++mt)
#pragma unroll
        for (int reg = 0; reg < 4; ++reg) {
          const int row = mt * 16 + g * 4 + reg;
          const float z = acc[mt][n2][reg] + bgc;
          su[SH_OB + row * 256 + col] = f2bf(1.f / (1.f + __expf(-z)));
        }
    }
  }
  barrier_lds();  // B5

  // ---- ph7: out = h + gate*any_real*((fused-mu)*rstd*lnw+lnb) -------------
  {
    const int half = t >> 8, col = t & 255;
    const float lw = lnw[col], lb = lnb[col];
#pragma unroll
    for (int i = 0; i < 16; ++i) {
      const int r = i * 2 + half;
      const float mu = s_sc[r * 12 + 8], inv = s_sc[r * 12 + 9], ar = s_sc[r * 12 + 6];
      const float f = bf2f(su[SH_QK + ((r * 256 + col) ^ ((r & 7) << 3))]);
      const float gt = bf2f(su[SH_OB + r * 256 + col]) * ar;
      const float upd = (f - mu) * inv * lw + lb;
      out[(row0 + r) * 256 + col] = h[(row0 + r) * 256 + col] + gt * upd;
    }
  }
}

extern "C" void kernel_launch(void* const* d_in, const int* in_sizes, int n_in, void* d_out,
                              int out_size, void* d_ws, size_t ws_size, hipStream_t stream) {
  const float* h = (const float*)d_in[0];
  const float* obs = (const float*)d_in[1];
  const float* st = (const float*)d_in[2];
  const void* vd = d_in[3];
  const float* Wq = (const float*)d_in[4];
  const float* bq = (const float*)d_in[5];
  const float* Wk = (const float*)d_in[6];
  const float* bk = (const float*)d_in[7];
  const float* Wv = (const float*)d_in[8];
  const float* bv = (const float*)d_in[9];
  const float* nk = (const float*)d_in[10];
  const float* nv = (const float*)d_in[11];
  const float* w0 = (const float*)d_in[12];
  const float* b0 = (const float*)d_in[13];
  const float* w1 = (const float*)d_in[14];
  const float* b1 = (const float*)d_in[15];
  const float* w2 = (const float*)d_in[16];
  const float* b2 = (const float*)d_in[17];
  const float* Wg = (const float*)d_in[18];
  const float* bg = (const float*)d_in[19];
  const float* lnw = (const float*)d_in[20];
  const float* lnb = (const float*)d_in[21];
  float* out = (float*)d_out;
  float* W = (float*)d_ws;
  const int L = in_sizes[0] / 256;

  k_zero<<<1, 64, 0, stream>>>((int*)d_ws);
  k_flag<<<256, 256, 0, stream>>>((const unsigned int*)vd, L, (int*)d_ws);
  k_prep<<<673, 256, 0, stream>>>(Wq, bq, Wk, bk, Wv, bv, nk, w1, w2, b2, Wg, W);
  k_main<<<L / Tr, 512, 0, stream>>>(h, obs, st, vd, w0, b0, b1, bg, lnw, lnb, nv, W,
                                     (const int*)d_ws, out);
}